// Round 3
// baseline (612.952 us; speedup 1.0000x reference)
//
#include <hip/hip_runtime.h>
#include <hip/hip_bf16.h>

#define NB 16
#define NA 1614

// ---------------- conv1: rpn_feature [16,2048,14,14] * w[128,2048,3,3] pad1 ----------------
// grid 1024 = 8 kc(256 ic) x 8 oct(16 oc) x 16 b. Block 256 thr: thread = 2 oc x 7 cols.
// tid: ocg = tid&7 (oc = oc0+ocg*2+{0,1}), posg = tid>>3: xh = posg>>4 (wave-uniform), y = posg&15.
// LDS rows padded to 20 floats -> conflict-free b128 reads (y*20 mod 32 all distinct).

template<int XOFF>
__device__ __forceinline__ void conv1_inner(const float* __restrict__ si,
                                            const float* __restrict__ swp,
                                            float acc[2][7]) {
#pragma unroll
  for (int ky = 0; ky < 3; ky++) {
    const float4 a = *(const float4*)(si + ky * 20);
    const float4 b = *(const float4*)(si + ky * 20 + 4);
    const float4 c = *(const float4*)(si + ky * 20 + 8);
    const float iv[12] = {a.x, a.y, a.z, a.w, b.x, b.y, b.z, b.w, c.x, c.y, c.z, c.w};
#pragma unroll
    for (int kx = 0; kx < 3; kx++) {
      const float2 wv = *(const float2*)(swp + (ky * 3 + kx) * 20);
#pragma unroll
      for (int x = 0; x < 7; x++) {
        const float v = iv[XOFF + x + kx];
        acc[0][x] = fmaf(wv.x, v, acc[0][x]);
        acc[1][x] = fmaf(wv.y, v, acc[1][x]);
      }
    }
  }
}

__global__ __launch_bounds__(256, 4)
void conv1_part(const float* __restrict__ in, const float* __restrict__ w,
                float* __restrict__ part) {
  const int bid = blockIdx.x;
  const int kc  = bid & 7;
  const int oct = (bid >> 3) & 7;
  const int b   = bid >> 6;
  const int ic0 = kc * 256;
  const int oc0 = oct * 16;
  const int tid = threadIdx.x;
  const int ocg  = tid & 7;
  const int posg = tid >> 3;
  const int xh   = posg >> 4;      // wave-uniform
  const int y    = posg & 15;      // rows 14,15 are pad, discarded

  __shared__ float s_in[16 * 360];   // [ch16][row18][col20pad]; tile col t = input col t-1
  __shared__ float s_w[16 * 180];    // [ch16][tap9][20pad: oc16]

  float acc[2][7] = {};

  const float* inb = in + (size_t)b * 2048 * 196;
  const int ivb = y * 20 + xh * 4;

  for (int icb = 0; icb < 256; icb += 16) {
    __syncthreads();
    // stage input: 16 ch x 18 rows x 16 cols (cols 16-19 pad, never read)
#pragma unroll
    for (int r = 0; r < 18; r++) {
      const int e = tid + 256 * r;               // 0..4607
      const int ch = e / 288, idx = e - ch * 288;
      const int tr = idx >> 4, tc = idx & 15;
      const int iy = tr - 1, ix = tc - 1;
      float v = 0.f;
      if ((unsigned)iy < 14u && (unsigned)ix < 14u)
        v = inb[(size_t)(ic0 + icb + ch) * 196 + iy * 14 + ix];
      s_in[ch * 360 + tr * 20 + tc] = v;
    }
    // stage weights: 16 ch x 9 tap x 16 oc (global: 144 contiguous floats per oc)
#pragma unroll
    for (int r = 0; r < 9; r++) {
      const int e = tid + 256 * r;               // 0..2303
      const int oc = e / 144, rem = e - oc * 144;
      const int ch = rem / 9, tap = rem - ch * 9;
      s_w[ch * 180 + tap * 20 + oc] =
          w[(size_t)(oc0 + oc) * 18432 + (size_t)(ic0 + icb) * 9 + rem];
    }
    __syncthreads();

    if (xh == 0) {
      for (int ic = 0; ic < 16; ic++)
        conv1_inner<0>(s_in + ic * 360 + ivb, s_w + ic * 180 + ocg * 2, acc);
    } else {
      for (int ic = 0; ic < 16; ic++)
        conv1_inner<3>(s_in + ic * 360 + ivb, s_w + ic * 180 + ocg * 2, acc);
    }
  }

  if (y < 14) {
    float* po = part + (((size_t)kc * NB + b) * 128 + oc0 + ocg * 2) * 196 + y * 14 + xh * 7;
#pragma unroll
    for (int i = 0; i < 2; i++)
#pragma unroll
      for (int x = 0; x < 7; x++)
        po[(size_t)i * 196 + x] = acc[i][x];
  }
}

__global__ void conv1_finish(const float* __restrict__ part,
                             const float* __restrict__ bias,
                             float* __restrict__ d1) {
  const int i4 = blockIdx.x * 256 + threadIdx.x;
  if (i4 >= NB * 128 * 49) return;
  const int i = i4 * 4;
  const int oc = (i / 196) & 127;
  const float bb = bias[oc];
  float4 s = {bb, bb, bb, bb};
#pragma unroll
  for (int k = 0; k < 8; k++) {
    const float4 p = *(const float4*)(part + (size_t)k * (NB * 128 * 196) + i);
    s.x += p.x; s.y += p.y; s.z += p.z; s.w += p.w;
  }
  s.x = fmaxf(s.x, 0.f); s.y = fmaxf(s.y, 0.f);
  s.z = fmaxf(s.z, 0.f); s.w = fmaxf(s.w, 0.f);
  *(float4*)(d1 + i) = s;
}

// ---------------- conv2: d1 [16,128,14,14] -> partials, stride2 pad1 ----------------
// grid 256 = 4 kc(32 ic) x 4 oct(32 oc) x 16 b. Thread: ocl = tid>>3, row rw = tid&7 (rw<7).
__global__ void conv2_part(const float* __restrict__ d1, const float* __restrict__ w,
                           float* __restrict__ p2) {
  const int bid = blockIdx.x;
  const int kc = bid & 3, oct = (bid >> 2) & 3, b = bid >> 4;
  const int ic0 = kc * 32, oc0 = oct * 32;
  const int tid = threadIdx.x;
  const int ocl = tid >> 3, rw = tid & 7;

  __shared__ float s_in[32 * 320];   // [ch32][row16][col20pad]; tile r,c = input r-1,c-1
  __shared__ float s_w[32 * 324];    // [ch32][tap9][36pad: oc32]

  // stage input: 32 ch x 16 x 16
#pragma unroll
  for (int r = 0; r < 32; r++) {
    const int e = tid + 256 * r;
    const int ch = e >> 8, idx = e & 255;
    const int tr = idx >> 4, tc = idx & 15;
    const int iy = tr - 1, ix = tc - 1;
    float v = 0.f;
    if ((unsigned)iy < 14u && (unsigned)ix < 14u)
      v = d1[((size_t)b * 128 + ic0 + ch) * 196 + iy * 14 + ix];
    s_in[ch * 320 + tr * 20 + tc] = v;
  }
  // stage weights: 32 oc x (32 ch x 9) contiguous runs of 288
#pragma unroll
  for (int r = 0; r < 36; r++) {
    const int e = tid + 256 * r;
    const int oc = e / 288, rem = e - oc * 288;
    const int ch = rem / 9, tap = rem - ch * 9;
    s_w[ch * 324 + tap * 36 + oc] =
        w[(size_t)(oc0 + oc) * 1152 + (size_t)ic0 * 9 + rem];
  }
  __syncthreads();

  if (rw < 7) {
    float acc[7] = {};
    for (int ic = 0; ic < 32; ic++) {
      const float* wrow = s_w + ic * 324 + ocl;
      const float* irow = s_in + ic * 320;
#pragma unroll
      for (int ky = 0; ky < 3; ky++) {
        const float* r = irow + (2 * rw + ky) * 20;
        const float4 f0 = *(const float4*)(r);
        const float4 f1 = *(const float4*)(r + 4);
        const float4 f2 = *(const float4*)(r + 8);
        const float4 f3 = *(const float4*)(r + 12);
        const float ev[8] = {f0.x, f0.z, f1.x, f1.z, f2.x, f2.z, f3.x, f3.z};
        const float od[7] = {f0.y, f0.w, f1.y, f1.w, f2.y, f2.w, f3.y};
        const float w0 = wrow[(ky * 3 + 0) * 36];
        const float w1 = wrow[(ky * 3 + 1) * 36];
        const float w2 = wrow[(ky * 3 + 2) * 36];
#pragma unroll
        for (int x = 0; x < 7; x++)
          acc[x] = fmaf(w0, ev[x], fmaf(w1, od[x], fmaf(w2, ev[x + 1], acc[x])));
      }
    }
    float* po = p2 + (((size_t)kc * NB + b) * 128 + oc0 + ocl) * 49 + rw * 7;
#pragma unroll
    for (int x = 0; x < 7; x++) po[x] = acc[x];
  }
}

__global__ void conv2_finish(const float* __restrict__ p2, const float* __restrict__ bias,
                             float* __restrict__ d2) {
  const int i = blockIdx.x * 256 + threadIdx.x;
  if (i >= NB * 128 * 49) return;
  const int oc = (i / 49) & 127;
  float s = bias[oc];
#pragma unroll
  for (int k = 0; k < 4; k++) s += p2[(size_t)k * (NB * 128 * 49) + i];
  d2[i] = fmaxf(s, 0.f);
}

// ---------------- conv3: d2 [16,128,7,7] -> partials, stride2 pad1 ----------------
// grid 256 = 2 kc(64 ic) x 8 oct(16 oc) x 16 b. Thread: oc = tid>>4, p = tid&15.
__global__ void conv3_part(const float* __restrict__ d2, const float* __restrict__ w,
                           float* __restrict__ p3) {
  const int bid = blockIdx.x;
  const int kc = bid & 1, oct = (bid >> 1) & 7, b = bid >> 4;
  const int ic0 = kc * 64, oc0 = oct * 16;
  const int tid = threadIdx.x;
  const int oc = tid >> 4, p = tid & 15;
  const int y = p >> 2, x = p & 3;

  __shared__ float s_in[64 * 108];   // [ch64][row9][col12pad]
  __shared__ float s_w[64 * 144];    // [ch64][tap9][16: oc]

#pragma unroll
  for (int r = 0; r < 21; r++) {
    const int e = tid + 256 * r;
    if (e < 64 * 81) {
      const int ch = e / 81, idx = e - ch * 81;
      const int tr = idx / 9, tc = idx - tr * 9;
      const int iy = tr - 1, ix = tc - 1;
      float v = 0.f;
      if ((unsigned)iy < 7u && (unsigned)ix < 7u)
        v = d2[((size_t)b * 128 + ic0 + ch) * 49 + iy * 7 + ix];
      s_in[ch * 108 + tr * 12 + tc] = v;
    }
  }
#pragma unroll
  for (int r = 0; r < 36; r++) {
    const int e = tid + 256 * r;
    const int o = e / 576, rem = e - o * 576;
    const int ch = rem / 9, tap = rem - ch * 9;
    s_w[ch * 144 + tap * 16 + o] =
        w[(size_t)(oc0 + o) * 1152 + (size_t)ic0 * 9 + rem];
  }
  __syncthreads();

  float acc = 0.f;
  for (int ic = 0; ic < 64; ic++) {
    const float* wrow = s_w + ic * 144 + oc;
    const float* irow = s_in + ic * 108 + 2 * y * 12 + 2 * x;
#pragma unroll
    for (int ky = 0; ky < 3; ky++)
#pragma unroll
      for (int kx = 0; kx < 3; kx++)
        acc = fmaf(wrow[(ky * 3 + kx) * 16], irow[ky * 12 + kx], acc);
  }
  p3[(((size_t)kc * NB + b) * 128 + oc0 + oc) * 16 + p] = acc;
}

__global__ void conv3_finish(const float* __restrict__ p3, const float* __restrict__ bias,
                             float* __restrict__ d3) {
  const int i = blockIdx.x * 256 + threadIdx.x;
  if (i >= NB * 128 * 16) return;
  const int oc = (i >> 4) & 127;
  float s = bias[oc] + p3[i] + p3[(size_t)(NB * 128 * 16) + i];
  d3[i] = fmaxf(s, 0.f);
}

// ---------------- tidy 1x1 convs -> rpn_score [16,1614] ----------------
__global__ void tidy_kernel(const float* __restrict__ d1, const float* __restrict__ d2,
                            const float* __restrict__ d3,
                            const float* __restrict__ w1, const float* __restrict__ b1,
                            const float* __restrict__ w2, const float* __restrict__ b2,
                            const float* __restrict__ w3, const float* __restrict__ b3,
                            float* __restrict__ score) {
  int i = blockIdx.x * 256 + threadIdx.x;
  if (i >= NB * NA) return;
  int b = i / NA, j = i - b * NA;
  float s;
  if (j < 1176) {
    int oc = j / 196, p = j - oc * 196;
    const float* in = d1 + (size_t)b * 128 * 196 + p;
    const float* w = w1 + oc * 128;
    s = b1[oc];
#pragma unroll 8
    for (int ic = 0; ic < 128; ic++) s += in[(size_t)ic * 196] * w[ic];
  } else if (j < 1470) {
    int jj = j - 1176;
    int oc = jj / 49, p = jj - oc * 49;
    const float* in = d2 + (size_t)b * 128 * 49 + p;
    const float* w = w2 + oc * 128;
    s = b2[oc];
#pragma unroll 8
    for (int ic = 0; ic < 128; ic++) s += in[(size_t)ic * 49] * w[ic];
  } else {
    int jj = j - 1470;
    int oc = jj / 16, p = jj & 15;
    const float* in = d3 + (size_t)b * 128 * 16 + p;
    const float* w = w3 + oc * 128;
    s = b3[oc];
#pragma unroll 8
    for (int ic = 0; ic < 128; ic++) s += in[(size_t)ic * 16] * w[ic];
  }
  score[i] = s;
}

// ---------------- NMS: per batch, TOPN=4, IoU>0.25 suppress ----------------
__global__ void nms_kernel(const float* __restrict__ score, const int* __restrict__ anchors,
                           float* __restrict__ out_idx, float* __restrict__ out_prob,
                           float* __restrict__ sel) {
  __shared__ float s_sc[NA];
  __shared__ float s_bx[NA * 4];
  __shared__ float r_s[256];
  __shared__ int r_i[256];
  const int b = blockIdx.x, tid = threadIdx.x;

  for (int i = tid; i < NA; i += 256) {
    s_sc[i] = score[b * NA + i];
    s_bx[i * 4 + 0] = (float)anchors[i * 4 + 0];
    s_bx[i * 4 + 1] = (float)anchors[i * 4 + 1];
    s_bx[i * 4 + 2] = (float)anchors[i * 4 + 2];
    s_bx[i * 4 + 3] = (float)anchors[i * 4 + 3];
  }
  __syncthreads();

  for (int t = 0; t < 4; t++) {
    float bs = -__builtin_inff();
    int bi = NA;
    for (int i = tid; i < NA; i += 256) {
      float s = s_sc[i];
      if (s > bs || (s == bs && i < bi)) { bs = s; bi = i; }
    }
    r_s[tid] = bs; r_i[tid] = bi;
    __syncthreads();
    for (int off = 128; off > 0; off >>= 1) {
      if (tid < off) {
        float s2 = r_s[tid + off]; int i2 = r_i[tid + off];
        if (s2 > r_s[tid] || (s2 == r_s[tid] && i2 < r_i[tid])) { r_s[tid] = s2; r_i[tid] = i2; }
      }
      __syncthreads();
    }
    const int idx = r_i[0];
    const float by0 = s_bx[idx * 4 + 0], bx0 = s_bx[idx * 4 + 1];
    const float by1 = s_bx[idx * 4 + 2], bx1 = s_bx[idx * 4 + 3];
    if (tid == 0) {
      out_idx[b * 4 + t] = (float)idx;
      out_prob[b * 4 + t] = s_sc[idx];
      sel[(b * 4 + t) * 4 + 0] = by0;
      sel[(b * 4 + t) * 4 + 1] = bx0;
      sel[(b * 4 + t) * 4 + 2] = by1;
      sel[(b * 4 + t) * 4 + 3] = bx1;
    }
    __syncthreads();
    const float a = (by1 - by0) * (bx1 - bx0);
    for (int i = tid; i < NA; i += 256) {
      float cy0 = s_bx[i * 4 + 0], cx0 = s_bx[i * 4 + 1];
      float cy1 = s_bx[i * 4 + 2], cx1 = s_bx[i * 4 + 3];
      float yy0 = fmaxf(by0, cy0), xx0 = fmaxf(bx0, cx0);
      float yy1 = fminf(by1, cy1), xx1 = fminf(bx1, cx1);
      float inter = fmaxf(yy1 - yy0, 0.f) * fmaxf(xx1 - xx0, 0.f);
      float ar = (cy1 - cy0) * (cx1 - cx0);
      float iou = inter / (a + ar - inter);
      if (iou > 0.25f) s_sc[i] = -__builtin_inff();
    }
    __syncthreads();
  }
}

// ---------------- crop+bilinear resize to [16,4,3,224,224] ----------------
__global__ void crop_kernel(const float* __restrict__ x, const float* __restrict__ sel,
                            float* __restrict__ out) {
  long long i = (long long)blockIdx.x * 256 + threadIdx.x;
  const long long total = (long long)NB * 4 * 3 * 224 * 224;
  if (i >= total) return;
  int px = (int)(i % 224);
  long long t = i / 224;
  int py = (int)(t % 224); t /= 224;
  int ch = (int)(t % 3);  t /= 3;
  int n  = (int)(t % 4);
  int b  = (int)(t / 4);

  const float* bx = sel + (b * 4 + n) * 4;
  const float y0 = bx[0], x0 = bx[1], y1 = bx[2], x1 = bx[3];

  float ty = (float)py / 223.0f;
  float cy = y0 + (y1 - 1.0f - y0) * ty;
  float cyf = floorf(cy);
  int ylo = (int)cyf; ylo = ylo < 0 ? 0 : (ylo > 895 ? 895 : ylo);
  int yhi = ylo + 1 > 895 ? 895 : ylo + 1;
  float wy = cy - cyf;

  float tx = (float)px / 223.0f;
  float cx = x0 + (x1 - 1.0f - x0) * tx;
  float cxf = floorf(cx);
  int xlo = (int)cxf; xlo = xlo < 0 ? 0 : (xlo > 895 ? 895 : xlo);
  int xhi = xlo + 1 > 895 ? 895 : xlo + 1;
  float wx = cx - cxf;

  const float* img = x + ((size_t)b * 3 + ch) * 448 * 448;
  auto g = [&](int yy, int xx) -> float {
    yy -= 224; xx -= 224;
    if ((unsigned)yy < 448u && (unsigned)xx < 448u)
      return img[(size_t)yy * 448 + xx];
    return 0.f;
  };
  float v00 = g(ylo, xlo), v01 = g(ylo, xhi);
  float v10 = g(yhi, xlo), v11 = g(yhi, xhi);
  float r = (1.f - wy) * ((1.f - wx) * v00 + wx * v01) +
            wy * ((1.f - wx) * v10 + wx * v11);
  out[i] = r;
}

extern "C" void kernel_launch(void* const* d_in, const int* in_sizes, int n_in,
                              void* d_out, int out_size, void* d_ws, size_t ws_size,
                              hipStream_t stream) {
  const float* x    = (const float*)d_in[0];
  const float* rpn  = (const float*)d_in[1];
  const int*   anc  = (const int*)d_in[2];
  const float* w_d1 = (const float*)d_in[3];
  const float* b_d1 = (const float*)d_in[4];
  const float* w_d2 = (const float*)d_in[5];
  const float* b_d2 = (const float*)d_in[6];
  const float* w_d3 = (const float*)d_in[7];
  const float* b_d3 = (const float*)d_in[8];
  const float* w_t1 = (const float*)d_in[9];
  const float* b_t1 = (const float*)d_in[10];
  const float* w_t2 = (const float*)d_in[11];
  const float* b_t2 = (const float*)d_in[12];
  const float* w_t3 = (const float*)d_in[13];
  const float* b_t3 = (const float*)d_in[14];

  float* out = (float*)d_out;
  float* ws = (float*)d_ws;

  float* part = ws;                       // 8*16*128*196 = 3,211,264 (dead after conv1_finish)
  float* p2   = ws;                       // 4*100,352 (reuses part region)
  float* p3   = ws + 401408;              // 2*32,768
  float* d1   = ws + 3211264;             // 401,408
  float* d2   = d1 + 401408;              // 100,352
  float* d3   = d2 + 100352;              // 32,768
  float* sel  = d3 + 32768;               // 256

  float* score    = out;                  // 25824
  float* out_idx  = out + 25824;          // 64
  float* out_prob = out + 25888;          // 64
  float* parts    = out + 25952;          // 9,633,792

  conv1_part<<<dim3(1024), dim3(256), 0, stream>>>(rpn, w_d1, part);
  conv1_finish<<<dim3(392), dim3(256), 0, stream>>>(part, b_d1, d1);
  conv2_part<<<dim3(256), dim3(256), 0, stream>>>(d1, w_d2, p2);
  conv2_finish<<<dim3(392), dim3(256), 0, stream>>>(p2, b_d2, d2);
  conv3_part<<<dim3(256), dim3(256), 0, stream>>>(d2, w_d3, p3);
  conv3_finish<<<dim3(128), dim3(256), 0, stream>>>(p3, b_d3, d3);
  tidy_kernel<<<dim3(101), dim3(256), 0, stream>>>(d1, d2, d3, w_t1, b_t1, w_t2, b_t2,
                                                   w_t3, b_t3, score);
  nms_kernel<<<dim3(16), dim3(256), 0, stream>>>(score, anc, out_idx, out_prob, sel);
  crop_kernel<<<dim3(37632), dim3(256), 0, stream>>>(x, sel, parts);
}

// Round 4
// 449.844 us; speedup vs baseline: 1.3626x; 1.3626x over previous
//
#include <hip/hip_runtime.h>
#include <hip/hip_bf16.h>

#define NB 16
#define NA 1614

typedef __bf16 bf16x8 __attribute__((ext_vector_type(8)));
typedef float f32x4 __attribute__((ext_vector_type(4)));

__device__ __forceinline__ unsigned short f2bf(float v) {
  unsigned u = __float_as_uint(v);
  unsigned r = (u + 0x7FFFu + ((u >> 16) & 1u)) >> 16;
  return (unsigned short)r;
}
__device__ __forceinline__ float bf2f(unsigned short s) {
  return __uint_as_float(((unsigned)s) << 16);
}

// ---------------- prep_w: w[128][2048][9] f32 -> wTh/wTl [9][128][2048] bf16 hi/lo ----------
__global__ void prep_w(const float* __restrict__ w, unsigned short* __restrict__ wTh,
                       unsigned short* __restrict__ wTl) {
  int e = blockIdx.x * 256 + threadIdx.x;
  if (e >= 9 * 128 * 2048) return;
  int tap = e / (128 * 2048);
  int rem = e - tap * (128 * 2048);
  int oc = rem >> 11, ic = rem & 2047;
  float v = w[((size_t)oc * 2048 + ic) * 9 + tap];
  unsigned short h = f2bf(v);
  wTh[e] = h;
  wTl[e] = f2bf(v - bf2f(h));
}

// ---------------- conv1 MFMA: implicit GEMM, split-bf16, atomics into d1 ----------------
// grid 256 = kc(16, 128-ic) x b(16, fastest). Block: M=196(208) x N=128, 4 waves (7mf x 4nf).
// A staged per 32-ic kstep into padded 16x16 pos-grid (taps = LDS offsets); ic-stride 40.
__global__ __launch_bounds__(256, 1)
void conv1_mfma(const float* __restrict__ in, const unsigned short* __restrict__ wTh,
                const unsigned short* __restrict__ wTl, float* __restrict__ d1) {
  const int bid = blockIdx.x;
  const int b  = bid & 15;
  const int kc = bid >> 4;
  const int tid = threadIdx.x;
  const int wid = tid >> 6, lane = tid & 63;
  const int wm = wid & 1, wn = wid >> 1;        // M-half, N-half
  const int q = lane >> 4, ln = lane & 15;

  __shared__ unsigned short sAh[256 * 40];   // [pospad256][ic32 +8pad]
  __shared__ unsigned short sAl[256 * 40];
  __shared__ unsigned short sBh[128 * 40];   // [oc128][ic32 +8pad]
  __shared__ unsigned short sBl[128 * 40];

  // zero A planes once (borders stay zero forever)
  for (int e = tid; e < 5120; e += 256) {
    ((unsigned int*)sAh)[e] = 0u;
    ((unsigned int*)sAl)[e] = 0u;
  }

  // per-lane A base offsets (tap (0,0)): padded pos = y*16+x, elem off = pos*40 + q*8
  int abase[7];
#pragma unroll
  for (int mf = 0; mf < 7; mf++) {
    int row = wm * 112 + mf * 16 + ln;
    int y = row / 14, x = row - y * 14;
    abase[mf] = ((row < 196) ? (y * 16 + x) : 0) * 40 + q * 8;
  }
  const int bbase = (wn * 64 + ln) * 40 + q * 8;

  f32x4 acc[7][4];
#pragma unroll
  for (int mf = 0; mf < 7; mf++)
#pragma unroll
    for (int nf = 0; nf < 4; nf++) acc[mf][nf] = (f32x4){0.f, 0.f, 0.f, 0.f};

  const float* inb = in + (size_t)b * 2048 * 196;

  for (int ks = 0; ks < 4; ks++) {
    const int icg0 = kc * 128 + ks * 32;
    for (int tap = 0; tap < 9; tap++) {
      __syncthreads();
      if (tap == 0) {
        // stage A: 32 ic x 196 pos, f32 -> hi/lo bf16, into padded grid
#pragma unroll
        for (int r = 0; r < 25; r++) {
          int e = tid + 256 * r;
          if (e < 6272) {
            int icl = e & 31, posl = e >> 5;
            float v = inb[(size_t)(icg0 + icl) * 196 + posl];
            unsigned short h = f2bf(v);
            unsigned short l = f2bf(v - bf2f(h));
            int py = posl / 14, px = posl - py * 14;
            int ad = ((py + 1) * 16 + px + 1) * 40 + icl;
            sAh[ad] = h;
            sAl[ad] = l;
          }
        }
      }
      // stage B: 128 oc x 32 ic for this tap
#pragma unroll
      for (int pass = 0; pass < 2; pass++) {
        int t = tid + pass * 256;
        int oc = t >> 2, icl0 = (t & 3) * 8;
        size_t goff = (((size_t)tap * 128 + oc) << 11) + icg0 + icl0;
        uint4 vh = *(const uint4*)(wTh + goff);
        uint4 vl = *(const uint4*)(wTl + goff);
        *(uint4*)(sBh + oc * 40 + icl0) = vh;
        *(uint4*)(sBl + oc * 40 + icl0) = vl;
      }
      __syncthreads();

      const int t40 = ((tap / 3) * 16 + (tap % 3)) * 40;
      bf16x8 bh[4], bl[4];
#pragma unroll
      for (int nf = 0; nf < 4; nf++) {
        bh[nf] = *(const bf16x8*)(sBh + bbase + nf * 640);
        bl[nf] = *(const bf16x8*)(sBl + bbase + nf * 640);
      }
#pragma unroll
      for (int mf = 0; mf < 7; mf++) {
        bf16x8 ah = *(const bf16x8*)(sAh + abase[mf] + t40);
        bf16x8 al = *(const bf16x8*)(sAl + abase[mf] + t40);
#pragma unroll
        for (int nf = 0; nf < 4; nf++) {
          acc[mf][nf] = __builtin_amdgcn_mfma_f32_16x16x32_bf16(ah, bh[nf], acc[mf][nf], 0, 0, 0);
          acc[mf][nf] = __builtin_amdgcn_mfma_f32_16x16x32_bf16(al, bh[nf], acc[mf][nf], 0, 0, 0);
          acc[mf][nf] = __builtin_amdgcn_mfma_f32_16x16x32_bf16(ah, bl[nf], acc[mf][nf], 0, 0, 0);
        }
      }
    }
  }

  // write out: C row = pos (quad*4+reg), col = oc (lane&15); split-K via atomicAdd
#pragma unroll
  for (int mf = 0; mf < 7; mf++) {
    const int row0 = wm * 112 + mf * 16 + q * 4;
#pragma unroll
    for (int nf = 0; nf < 4; nf++) {
      const int oc = wn * 64 + nf * 16 + ln;
      float* dst = d1 + ((size_t)b * 128 + oc) * 196;
#pragma unroll
      for (int r = 0; r < 4; r++) {
        const int row = row0 + r;
        if (row < 196) atomicAdd(dst + row, acc[mf][nf][r]);
      }
    }
  }
}

__global__ void conv1_finish(float* __restrict__ d1, const float* __restrict__ bias) {
  const int i = blockIdx.x * 256 + threadIdx.x;
  if (i >= NB * 128 * 196) return;
  const int oc = (i / 196) & 127;
  d1[i] = fmaxf(d1[i] + bias[oc], 0.f);
}

// ---------------- conv2: d1 [16,128,14,14] -> partials, stride2 pad1 ----------------
__global__ void conv2_part(const float* __restrict__ d1, const float* __restrict__ w,
                           float* __restrict__ p2) {
  const int bid = blockIdx.x;
  const int kc = bid & 3, oct = (bid >> 2) & 3, b = bid >> 4;
  const int ic0 = kc * 32, oc0 = oct * 32;
  const int tid = threadIdx.x;
  const int ocl = tid >> 3, rw = tid & 7;

  __shared__ float s_in[32 * 320];
  __shared__ float s_w[32 * 324];

#pragma unroll
  for (int r = 0; r < 32; r++) {
    const int e = tid + 256 * r;
    const int ch = e >> 8, idx = e & 255;
    const int tr = idx >> 4, tc = idx & 15;
    const int iy = tr - 1, ix = tc - 1;
    float v = 0.f;
    if ((unsigned)iy < 14u && (unsigned)ix < 14u)
      v = d1[((size_t)b * 128 + ic0 + ch) * 196 + iy * 14 + ix];
    s_in[ch * 320 + tr * 20 + tc] = v;
  }
#pragma unroll
  for (int r = 0; r < 36; r++) {
    const int e = tid + 256 * r;
    const int oc = e / 288, rem = e - oc * 288;
    const int ch = rem / 9, tap = rem - ch * 9;
    s_w[ch * 324 + tap * 36 + oc] =
        w[(size_t)(oc0 + oc) * 1152 + (size_t)ic0 * 9 + rem];
  }
  __syncthreads();

  if (rw < 7) {
    float acc[7] = {};
    for (int ic = 0; ic < 32; ic++) {
      const float* wrow = s_w + ic * 324 + ocl;
      const float* irow = s_in + ic * 320;
#pragma unroll
      for (int ky = 0; ky < 3; ky++) {
        const float* r = irow + (2 * rw + ky) * 20;
        const float4 f0 = *(const float4*)(r);
        const float4 f1 = *(const float4*)(r + 4);
        const float4 f2 = *(const float4*)(r + 8);
        const float4 f3 = *(const float4*)(r + 12);
        const float ev[8] = {f0.x, f0.z, f1.x, f1.z, f2.x, f2.z, f3.x, f3.z};
        const float od[7] = {f0.y, f0.w, f1.y, f1.w, f2.y, f2.w, f3.y};
        const float w0 = wrow[(ky * 3 + 0) * 36];
        const float w1 = wrow[(ky * 3 + 1) * 36];
        const float w2 = wrow[(ky * 3 + 2) * 36];
#pragma unroll
        for (int x = 0; x < 7; x++)
          acc[x] = fmaf(w0, ev[x], fmaf(w1, od[x], fmaf(w2, ev[x + 1], acc[x])));
      }
    }
    float* po = p2 + (((size_t)kc * NB + b) * 128 + oc0 + ocl) * 49 + rw * 7;
#pragma unroll
    for (int x = 0; x < 7; x++) po[x] = acc[x];
  }
}

__global__ void conv2_finish(const float* __restrict__ p2, const float* __restrict__ bias,
                             float* __restrict__ d2) {
  const int i = blockIdx.x * 256 + threadIdx.x;
  if (i >= NB * 128 * 49) return;
  const int oc = (i / 49) & 127;
  float s = bias[oc];
#pragma unroll
  for (int k = 0; k < 4; k++) s += p2[(size_t)k * (NB * 128 * 49) + i];
  d2[i] = fmaxf(s, 0.f);
}

// ---------------- conv3: d2 [16,128,7,7] -> partials, stride2 pad1 ----------------
__global__ void conv3_part(const float* __restrict__ d2, const float* __restrict__ w,
                           float* __restrict__ p3) {
  const int bid = blockIdx.x;
  const int kc = bid & 1, oct = (bid >> 1) & 7, b = bid >> 4;
  const int ic0 = kc * 64, oc0 = oct * 16;
  const int tid = threadIdx.x;
  const int oc = tid >> 4, p = tid & 15;
  const int y = p >> 2, x = p & 3;

  __shared__ float s_in[64 * 108];
  __shared__ float s_w[64 * 144];

#pragma unroll
  for (int r = 0; r < 21; r++) {
    const int e = tid + 256 * r;
    if (e < 64 * 81) {
      const int ch = e / 81, idx = e - ch * 81;
      const int tr = idx / 9, tc = idx - tr * 9;
      const int iy = tr - 1, ix = tc - 1;
      float v = 0.f;
      if ((unsigned)iy < 7u && (unsigned)ix < 7u)
        v = d2[((size_t)b * 128 + ic0 + ch) * 49 + iy * 7 + ix];
      s_in[ch * 108 + tr * 12 + tc] = v;
    }
  }
#pragma unroll
  for (int r = 0; r < 36; r++) {
    const int e = tid + 256 * r;
    const int o = e / 576, rem = e - o * 576;
    const int ch = rem / 9, tap = rem - ch * 9;
    s_w[ch * 144 + tap * 16 + o] =
        w[(size_t)(oc0 + o) * 1152 + (size_t)ic0 * 9 + rem];
  }
  __syncthreads();

  float acc = 0.f;
  for (int ic = 0; ic < 64; ic++) {
    const float* wrow = s_w + ic * 144 + oc;
    const float* irow = s_in + ic * 108 + 2 * y * 12 + 2 * x;
#pragma unroll
    for (int ky = 0; ky < 3; ky++)
#pragma unroll
      for (int kx = 0; kx < 3; kx++)
        acc = fmaf(wrow[(ky * 3 + kx) * 16], irow[ky * 12 + kx], acc);
  }
  p3[(((size_t)kc * NB + b) * 128 + oc0 + oc) * 16 + p] = acc;
}

__global__ void conv3_finish(const float* __restrict__ p3, const float* __restrict__ bias,
                             float* __restrict__ d3) {
  const int i = blockIdx.x * 256 + threadIdx.x;
  if (i >= NB * 128 * 16) return;
  const int oc = (i >> 4) & 127;
  float s = bias[oc] + p3[i] + p3[(size_t)(NB * 128 * 16) + i];
  d3[i] = fmaxf(s, 0.f);
}

// ---------------- tidy 1x1 convs -> rpn_score [16,1614] ----------------
__global__ void tidy_kernel(const float* __restrict__ d1, const float* __restrict__ d2,
                            const float* __restrict__ d3,
                            const float* __restrict__ w1, const float* __restrict__ b1,
                            const float* __restrict__ w2, const float* __restrict__ b2,
                            const float* __restrict__ w3, const float* __restrict__ b3,
                            float* __restrict__ score) {
  int i = blockIdx.x * 256 + threadIdx.x;
  if (i >= NB * NA) return;
  int b = i / NA, j = i - b * NA;
  float s;
  if (j < 1176) {
    int oc = j / 196, p = j - oc * 196;
    const float* in = d1 + (size_t)b * 128 * 196 + p;
    const float* w = w1 + oc * 128;
    s = b1[oc];
#pragma unroll 8
    for (int ic = 0; ic < 128; ic++) s += in[(size_t)ic * 196] * w[ic];
  } else if (j < 1470) {
    int jj = j - 1176;
    int oc = jj / 49, p = jj - oc * 49;
    const float* in = d2 + (size_t)b * 128 * 49 + p;
    const float* w = w2 + oc * 128;
    s = b2[oc];
#pragma unroll 8
    for (int ic = 0; ic < 128; ic++) s += in[(size_t)ic * 49] * w[ic];
  } else {
    int jj = j - 1470;
    int oc = jj / 16, p = jj & 15;
    const float* in = d3 + (size_t)b * 128 * 16 + p;
    const float* w = w3 + oc * 128;
    s = b3[oc];
#pragma unroll 8
    for (int ic = 0; ic < 128; ic++) s += in[(size_t)ic * 16] * w[ic];
  }
  score[i] = s;
}

// ---------------- NMS: per batch, TOPN=4, IoU>0.25 suppress ----------------
__global__ void nms_kernel(const float* __restrict__ score, const int* __restrict__ anchors,
                           float* __restrict__ out_idx, float* __restrict__ out_prob,
                           float* __restrict__ sel) {
  __shared__ float s_sc[NA];
  __shared__ float s_bx[NA * 4];
  __shared__ float r_s[256];
  __shared__ int r_i[256];
  const int b = blockIdx.x, tid = threadIdx.x;

  for (int i = tid; i < NA; i += 256) {
    s_sc[i] = score[b * NA + i];
    s_bx[i * 4 + 0] = (float)anchors[i * 4 + 0];
    s_bx[i * 4 + 1] = (float)anchors[i * 4 + 1];
    s_bx[i * 4 + 2] = (float)anchors[i * 4 + 2];
    s_bx[i * 4 + 3] = (float)anchors[i * 4 + 3];
  }
  __syncthreads();

  for (int t = 0; t < 4; t++) {
    float bs = -__builtin_inff();
    int bi = NA;
    for (int i = tid; i < NA; i += 256) {
      float s = s_sc[i];
      if (s > bs || (s == bs && i < bi)) { bs = s; bi = i; }
    }
    r_s[tid] = bs; r_i[tid] = bi;
    __syncthreads();
    for (int off = 128; off > 0; off >>= 1) {
      if (tid < off) {
        float s2 = r_s[tid + off]; int i2 = r_i[tid + off];
        if (s2 > r_s[tid] || (s2 == r_s[tid] && i2 < r_i[tid])) { r_s[tid] = s2; r_i[tid] = i2; }
      }
      __syncthreads();
    }
    const int idx = r_i[0];
    const float by0 = s_bx[idx * 4 + 0], bx0 = s_bx[idx * 4 + 1];
    const float by1 = s_bx[idx * 4 + 2], bx1 = s_bx[idx * 4 + 3];
    if (tid == 0) {
      out_idx[b * 4 + t] = (float)idx;
      out_prob[b * 4 + t] = s_sc[idx];
      sel[(b * 4 + t) * 4 + 0] = by0;
      sel[(b * 4 + t) * 4 + 1] = bx0;
      sel[(b * 4 + t) * 4 + 2] = by1;
      sel[(b * 4 + t) * 4 + 3] = bx1;
    }
    __syncthreads();
    const float a = (by1 - by0) * (bx1 - bx0);
    for (int i = tid; i < NA; i += 256) {
      float cy0 = s_bx[i * 4 + 0], cx0 = s_bx[i * 4 + 1];
      float cy1 = s_bx[i * 4 + 2], cx1 = s_bx[i * 4 + 3];
      float yy0 = fmaxf(by0, cy0), xx0 = fmaxf(bx0, cx0);
      float yy1 = fminf(by1, cy1), xx1 = fminf(bx1, cx1);
      float inter = fmaxf(yy1 - yy0, 0.f) * fmaxf(xx1 - xx0, 0.f);
      float ar = (cy1 - cy0) * (cx1 - cx0);
      float iou = inter / (a + ar - inter);
      if (iou > 0.25f) s_sc[i] = -__builtin_inff();
    }
    __syncthreads();
  }
}

// ---------------- crop+bilinear resize to [16,4,3,224,224] ----------------
__global__ void crop_kernel(const float* __restrict__ x, const float* __restrict__ sel,
                            float* __restrict__ out) {
  long long i = (long long)blockIdx.x * 256 + threadIdx.x;
  const long long total = (long long)NB * 4 * 3 * 224 * 224;
  if (i >= total) return;
  int px = (int)(i % 224);
  long long t = i / 224;
  int py = (int)(t % 224); t /= 224;
  int ch = (int)(t % 3);  t /= 3;
  int n  = (int)(t % 4);
  int b  = (int)(t / 4);

  const float* bx = sel + (b * 4 + n) * 4;
  const float y0 = bx[0], x0 = bx[1], y1 = bx[2], x1 = bx[3];

  float ty = (float)py / 223.0f;
  float cy = y0 + (y1 - 1.0f - y0) * ty;
  float cyf = floorf(cy);
  int ylo = (int)cyf; ylo = ylo < 0 ? 0 : (ylo > 895 ? 895 : ylo);
  int yhi = ylo + 1 > 895 ? 895 : ylo + 1;
  float wy = cy - cyf;

  float tx = (float)px / 223.0f;
  float cx = x0 + (x1 - 1.0f - x0) * tx;
  float cxf = floorf(cx);
  int xlo = (int)cxf; xlo = xlo < 0 ? 0 : (xlo > 895 ? 895 : xlo);
  int xhi = xlo + 1 > 895 ? 895 : xlo + 1;
  float wx = cx - cxf;

  const float* img = x + ((size_t)b * 3 + ch) * 448 * 448;
  auto g = [&](int yy, int xx) -> float {
    yy -= 224; xx -= 224;
    if ((unsigned)yy < 448u && (unsigned)xx < 448u)
      return img[(size_t)yy * 448 + xx];
    return 0.f;
  };
  float v00 = g(ylo, xlo), v01 = g(ylo, xhi);
  float v10 = g(yhi, xlo), v11 = g(yhi, xhi);
  float r = (1.f - wy) * ((1.f - wx) * v00 + wx * v01) +
            wy * ((1.f - wx) * v10 + wx * v11);
  out[i] = r;
}

extern "C" void kernel_launch(void* const* d_in, const int* in_sizes, int n_in,
                              void* d_out, int out_size, void* d_ws, size_t ws_size,
                              hipStream_t stream) {
  const float* x    = (const float*)d_in[0];
  const float* rpn  = (const float*)d_in[1];
  const int*   anc  = (const int*)d_in[2];
  const float* w_d1 = (const float*)d_in[3];
  const float* b_d1 = (const float*)d_in[4];
  const float* w_d2 = (const float*)d_in[5];
  const float* b_d2 = (const float*)d_in[6];
  const float* w_d3 = (const float*)d_in[7];
  const float* b_d3 = (const float*)d_in[8];
  const float* w_t1 = (const float*)d_in[9];
  const float* b_t1 = (const float*)d_in[10];
  const float* w_t2 = (const float*)d_in[11];
  const float* b_t2 = (const float*)d_in[12];
  const float* w_t3 = (const float*)d_in[13];
  const float* b_t3 = (const float*)d_in[14];

  float* out = (float*)d_out;
  float* ws = (float*)d_ws;

  float* d1  = ws;                        // 401408 (conv1 accumulator, then activations)
  float* d2  = d1 + 401408;               // 100352
  float* d3  = d2 + 100352;               // 32768
  float* sel = d3 + 32768;                // 256
  float* p2  = sel + 256;                 // 401408
  float* p3  = p2 + 401408;               // 65536
  unsigned short* wTh = (unsigned short*)(p3 + 65536);   // 2359296 ush
  unsigned short* wTl = wTh + 2359296;                   // 2359296 ush

  float* score    = out;                  // 25824
  float* out_idx  = out + 25824;          // 64
  float* out_prob = out + 25888;          // 64
  float* parts    = out + 25952;          // 9,633,792

  hipMemsetAsync(d1, 0, (size_t)NB * 128 * 196 * sizeof(float), stream);
  prep_w<<<dim3(9216), dim3(256), 0, stream>>>(w_d1, wTh, wTl);
  conv1_mfma<<<dim3(256), dim3(256), 0, stream>>>(rpn, wTh, wTl, d1);
  conv1_finish<<<dim3(1568), dim3(256), 0, stream>>>(d1, b_d1);
  conv2_part<<<dim3(256), dim3(256), 0, stream>>>(d1, w_d2, p2);
  conv2_finish<<<dim3(392), dim3(256), 0, stream>>>(p2, b_d2, d2);
  conv3_part<<<dim3(256), dim3(256), 0, stream>>>(d2, w_d3, p3);
  conv3_finish<<<dim3(128), dim3(256), 0, stream>>>(p3, b_d3, d3);
  tidy_kernel<<<dim3(101), dim3(256), 0, stream>>>(d1, d2, d3, w_t1, b_t1, w_t2, b_t2,
                                                   w_t3, b_t3, score);
  nms_kernel<<<dim3(16), dim3(256), 0, stream>>>(score, anc, out_idx, out_prob, sel);
  crop_kernel<<<dim3(37632), dim3(256), 0, stream>>>(x, sel, parts);
}

// Round 5
// 306.675 us; speedup vs baseline: 1.9987x; 1.4668x over previous
//
#include <hip/hip_runtime.h>
#include <hip/hip_bf16.h>

#define NB 16
#define NA 1614

typedef __bf16 bf16x8 __attribute__((ext_vector_type(8)));
typedef float f32x4 __attribute__((ext_vector_type(4)));

__device__ __forceinline__ unsigned short f2bf(float v) {
  unsigned u = __float_as_uint(v);
  unsigned r = (u + 0x7FFFu + ((u >> 16) & 1u)) >> 16;
  return (unsigned short)r;
}
__device__ __forceinline__ float bf2f(unsigned short s) {
  return __uint_as_float(((unsigned)s) << 16);
}

// ---------------- prep_w: w[128][2048][9] f32 -> wTh/wTl [9][128][2048] bf16 hi/lo ----------
__global__ void prep_w(const float* __restrict__ w, unsigned short* __restrict__ wTh,
                       unsigned short* __restrict__ wTl) {
  int e = blockIdx.x * 256 + threadIdx.x;
  if (e >= 9 * 128 * 2048) return;
  int tap = e / (128 * 2048);
  int rem = e - tap * (128 * 2048);
  int oc = rem >> 11, ic = rem & 2047;
  float v = w[((size_t)oc * 2048 + ic) * 9 + tap];
  unsigned short h = f2bf(v);
  wTh[e] = h;
  wTl[e] = f2bf(v - bf2f(h));
}

// ---------------- conv1 MFMA: implicit GEMM, split-bf16 ----------------
// grid 512 = kc(16, 128-ic) x nh(2, 64-oc) x b(16, fastest). Block: M=196(224) x N=64,
// 4 waves = wm(2) x wn(2), each 7mf x 2nf. B register-prefetch pipeline across 36 taps.
// Epilogue: coalesced partial store to p1[kc] (atomic_mode=0) or atomicAdd d1 (=1).
__global__ __launch_bounds__(256, 3)
void conv1_mfma(const float* __restrict__ in, const unsigned short* __restrict__ wTh,
                const unsigned short* __restrict__ wTl, float* __restrict__ pout,
                int atomic_mode) {
  const int bid = blockIdx.x;
  const int b  = bid & 15;
  const int nh = (bid >> 4) & 1;
  const int kc = bid >> 5;
  const int tid = threadIdx.x;
  const int wid = tid >> 6, lane = tid & 63;
  const int wm = wid & 1, wn = wid >> 1;
  const int q = lane >> 4, ln = lane & 15;

  __shared__ unsigned short sAh[256 * 40];   // [pospad256][ic32 +8pad]
  __shared__ unsigned short sAl[256 * 40];
  __shared__ unsigned short sBh[64 * 40];    // [oc64][ic32 +8pad]
  __shared__ unsigned short sBl[64 * 40];

  for (int e = tid; e < 5120; e += 256) {
    ((unsigned int*)sAh)[e] = 0u;
    ((unsigned int*)sAl)[e] = 0u;
  }

  int abase[7];
#pragma unroll
  for (int mf = 0; mf < 7; mf++) {
    int row = wm * 112 + mf * 16 + ln;
    int y = row / 14, x = row - y * 14;
    abase[mf] = ((row < 196) ? (y * 16 + x) : 0) * 40 + q * 8;
  }

  f32x4 acc[7][2];
#pragma unroll
  for (int mf = 0; mf < 7; mf++)
#pragma unroll
    for (int nf = 0; nf < 2; nf++) acc[mf][nf] = (f32x4){0.f, 0.f, 0.f, 0.f};

  const float* inb = in + (size_t)b * 2048 * 196;

  // B staging map: thread -> (oc 0..63, icl0)
  const int boc = tid >> 2, bic0 = (tid & 3) * 8;
  const size_t bocbase = (size_t)(nh * 64 + boc) << 11;

  // preload it=0 (ks=0, tap=0)
  uint4 pvh, pvl;
  {
    size_t g = bocbase + kc * 128 + bic0;   // tap=0, ks=0
    pvh = *(const uint4*)(wTh + g);
    pvl = *(const uint4*)(wTl + g);
  }

  for (int it = 0; it < 36; it++) {
    const int ks = it / 9, tap = it - ks * 9;
    const int icg0 = kc * 128 + ks * 32;
    __syncthreads();   // prev iteration's sA/sB reads complete
    *(uint4*)(sBh + boc * 40 + bic0) = pvh;
    *(uint4*)(sBl + boc * 40 + bic0) = pvl;
    if (tap == 0) {
      // stage A: 32 ic x 196 pos, f32 -> hi/lo bf16, into padded 16x16 grid
#pragma unroll
      for (int r = 0; r < 25; r++) {
        int e = tid + 256 * r;
        if (e < 6272) {
          int icl = e & 31, posl = e >> 5;
          float v = inb[(size_t)(icg0 + icl) * 196 + posl];
          unsigned short h = f2bf(v);
          unsigned short l = f2bf(v - bf2f(h));
          int py = posl / 14, px = posl - py * 14;
          int ad = ((py + 1) * 16 + px + 1) * 40 + icl;
          sAh[ad] = h;
          sAl[ad] = l;
        }
      }
    }
    // prefetch next tap's B into registers (consumed after next barrier)
    {
      const int nit = (it < 35) ? it + 1 : 35;
      const int ks2 = nit / 9, tap2 = nit - ks2 * 9;
      size_t g = (size_t)tap2 * (128 * 2048) + bocbase + kc * 128 + ks2 * 32 + bic0;
      pvh = *(const uint4*)(wTh + g);
      pvl = *(const uint4*)(wTl + g);
    }
    __syncthreads();

    const int t40 = ((tap / 3) * 16 + (tap % 3)) * 40;
    bf16x8 bh[2], bl[2];
#pragma unroll
    for (int nf = 0; nf < 2; nf++) {
      const int bb = (wn * 32 + nf * 16 + ln) * 40 + q * 8;
      bh[nf] = *(const bf16x8*)(sBh + bb);
      bl[nf] = *(const bf16x8*)(sBl + bb);
    }
#pragma unroll
    for (int mf = 0; mf < 7; mf++) {
      bf16x8 ah = *(const bf16x8*)(sAh + abase[mf] + t40);
      bf16x8 al = *(const bf16x8*)(sAl + abase[mf] + t40);
#pragma unroll
      for (int nf = 0; nf < 2; nf++) {
        acc[mf][nf] = __builtin_amdgcn_mfma_f32_16x16x32_bf16(ah, bh[nf], acc[mf][nf], 0, 0, 0);
        acc[mf][nf] = __builtin_amdgcn_mfma_f32_16x16x32_bf16(al, bh[nf], acc[mf][nf], 0, 0, 0);
        acc[mf][nf] = __builtin_amdgcn_mfma_f32_16x16x32_bf16(ah, bl[nf], acc[mf][nf], 0, 0, 0);
      }
    }
  }

  // epilogue
  if (atomic_mode) {
#pragma unroll
    for (int mf = 0; mf < 7; mf++) {
      const int row0 = wm * 112 + mf * 16 + q * 4;
#pragma unroll
      for (int nf = 0; nf < 2; nf++) {
        const int oc = nh * 64 + wn * 32 + nf * 16 + ln;
        float* dst = pout + ((size_t)b * 128 + oc) * 196;
#pragma unroll
        for (int r = 0; r < 4; r++) {
          const int row = row0 + r;
          if (row < 196) atomicAdd(dst + row, acc[mf][nf][r]);
        }
      }
    }
  } else {
    // p1[kc][b][pos196][oc128], coalesced 64B segments
    float* pk = pout + ((size_t)kc * NB + b) * 196 * 128;
#pragma unroll
    for (int mf = 0; mf < 7; mf++) {
      const int row0 = wm * 112 + mf * 16 + q * 4;
#pragma unroll
      for (int nf = 0; nf < 2; nf++) {
        const int oc = nh * 64 + wn * 32 + nf * 16 + ln;
#pragma unroll
        for (int r = 0; r < 4; r++) {
          const int row = row0 + r;
          if (row < 196) pk[(size_t)row * 128 + oc] = acc[mf][nf][r];
        }
      }
    }
  }
}

// partials mode finish: sum 16 kc slabs + bias + relu, transpose to [b][oc][pos]
__global__ void conv1_finish_p(const float* __restrict__ p1, const float* __restrict__ bias,
                               float* __restrict__ d1) {
  const int i = blockIdx.x * 256 + threadIdx.x;
  if (i >= NB * 196 * 128) return;
  const int oc = i & 127;
  const int t = i >> 7;
  const int pos = t % 196, b = t / 196;
  float s = bias[oc];
#pragma unroll
  for (int k = 0; k < 16; k++) s += p1[(size_t)k * (NB * 196 * 128) + i];
  d1[((size_t)b * 128 + oc) * 196 + pos] = fmaxf(s, 0.f);
}

// atomic mode finish: bias + relu in place
__global__ void conv1_finish_a(float* __restrict__ d1, const float* __restrict__ bias) {
  const int i = blockIdx.x * 256 + threadIdx.x;
  if (i >= NB * 128 * 196) return;
  const int oc = (i / 196) & 127;
  d1[i] = fmaxf(d1[i] + bias[oc], 0.f);
}

// ---------------- conv2: d1 [16,128,14,14] -> partials, stride2 pad1 ----------------
__global__ void conv2_part(const float* __restrict__ d1, const float* __restrict__ w,
                           float* __restrict__ p2) {
  const int bid = blockIdx.x;
  const int kc = bid & 3, oct = (bid >> 2) & 3, b = bid >> 4;
  const int ic0 = kc * 32, oc0 = oct * 32;
  const int tid = threadIdx.x;
  const int ocl = tid >> 3, rw = tid & 7;

  __shared__ float s_in[32 * 320];
  __shared__ float s_w[32 * 324];

#pragma unroll
  for (int r = 0; r < 32; r++) {
    const int e = tid + 256 * r;
    const int ch = e >> 8, idx = e & 255;
    const int tr = idx >> 4, tc = idx & 15;
    const int iy = tr - 1, ix = tc - 1;
    float v = 0.f;
    if ((unsigned)iy < 14u && (unsigned)ix < 14u)
      v = d1[((size_t)b * 128 + ic0 + ch) * 196 + iy * 14 + ix];
    s_in[ch * 320 + tr * 20 + tc] = v;
  }
#pragma unroll
  for (int r = 0; r < 36; r++) {
    const int e = tid + 256 * r;
    const int oc = e / 288, rem = e - oc * 288;
    const int ch = rem / 9, tap = rem - ch * 9;
    s_w[ch * 324 + tap * 36 + oc] =
        w[(size_t)(oc0 + oc) * 1152 + (size_t)ic0 * 9 + rem];
  }
  __syncthreads();

  if (rw < 7) {
    float acc[7] = {};
    for (int ic = 0; ic < 32; ic++) {
      const float* wrow = s_w + ic * 324 + ocl;
      const float* irow = s_in + ic * 320;
#pragma unroll
      for (int ky = 0; ky < 3; ky++) {
        const float* r = irow + (2 * rw + ky) * 20;
        const float4 f0 = *(const float4*)(r);
        const float4 f1 = *(const float4*)(r + 4);
        const float4 f2 = *(const float4*)(r + 8);
        const float4 f3 = *(const float4*)(r + 12);
        const float ev[8] = {f0.x, f0.z, f1.x, f1.z, f2.x, f2.z, f3.x, f3.z};
        const float od[7] = {f0.y, f0.w, f1.y, f1.w, f2.y, f2.w, f3.y};
        const float w0 = wrow[(ky * 3 + 0) * 36];
        const float w1 = wrow[(ky * 3 + 1) * 36];
        const float w2 = wrow[(ky * 3 + 2) * 36];
#pragma unroll
        for (int x = 0; x < 7; x++)
          acc[x] = fmaf(w0, ev[x], fmaf(w1, od[x], fmaf(w2, ev[x + 1], acc[x])));
      }
    }
    float* po = p2 + (((size_t)kc * NB + b) * 128 + oc0 + ocl) * 49 + rw * 7;
#pragma unroll
    for (int x = 0; x < 7; x++) po[x] = acc[x];
  }
}

__global__ void conv2_finish(const float* __restrict__ p2, const float* __restrict__ bias,
                             float* __restrict__ d2) {
  const int i = blockIdx.x * 256 + threadIdx.x;
  if (i >= NB * 128 * 49) return;
  const int oc = (i / 49) & 127;
  float s = bias[oc];
#pragma unroll
  for (int k = 0; k < 4; k++) s += p2[(size_t)k * (NB * 128 * 49) + i];
  d2[i] = fmaxf(s, 0.f);
}

// ---------------- conv3: d2 [16,128,7,7] -> partials, stride2 pad1 ----------------
__global__ void conv3_part(const float* __restrict__ d2, const float* __restrict__ w,
                           float* __restrict__ p3) {
  const int bid = blockIdx.x;
  const int kc = bid & 1, oct = (bid >> 1) & 7, b = bid >> 4;
  const int ic0 = kc * 64, oc0 = oct * 16;
  const int tid = threadIdx.x;
  const int oc = tid >> 4, p = tid & 15;
  const int y = p >> 2, x = p & 3;

  __shared__ float s_in[64 * 108];
  __shared__ float s_w[64 * 144];

#pragma unroll
  for (int r = 0; r < 21; r++) {
    const int e = tid + 256 * r;
    if (e < 64 * 81) {
      const int ch = e / 81, idx = e - ch * 81;
      const int tr = idx / 9, tc = idx - tr * 9;
      const int iy = tr - 1, ix = tc - 1;
      float v = 0.f;
      if ((unsigned)iy < 7u && (unsigned)ix < 7u)
        v = d2[((size_t)b * 128 + ic0 + ch) * 49 + iy * 7 + ix];
      s_in[ch * 108 + tr * 12 + tc] = v;
    }
  }
#pragma unroll
  for (int r = 0; r < 36; r++) {
    const int e = tid + 256 * r;
    const int o = e / 576, rem = e - o * 576;
    const int ch = rem / 9, tap = rem - ch * 9;
    s_w[ch * 144 + tap * 16 + o] =
        w[(size_t)(oc0 + o) * 1152 + (size_t)ic0 * 9 + rem];
  }
  __syncthreads();

  float acc = 0.f;
  for (int ic = 0; ic < 64; ic++) {
    const float* wrow = s_w + ic * 144 + oc;
    const float* irow = s_in + ic * 108 + 2 * y * 12 + 2 * x;
#pragma unroll
    for (int ky = 0; ky < 3; ky++)
#pragma unroll
      for (int kx = 0; kx < 3; kx++)
        acc = fmaf(wrow[(ky * 3 + kx) * 16], irow[ky * 12 + kx], acc);
  }
  p3[(((size_t)kc * NB + b) * 128 + oc0 + oc) * 16 + p] = acc;
}

__global__ void conv3_finish(const float* __restrict__ p3, const float* __restrict__ bias,
                             float* __restrict__ d3) {
  const int i = blockIdx.x * 256 + threadIdx.x;
  if (i >= NB * 128 * 16) return;
  const int oc = (i >> 4) & 127;
  float s = bias[oc] + p3[i] + p3[(size_t)(NB * 128 * 16) + i];
  d3[i] = fmaxf(s, 0.f);
}

// ---------------- tidy 1x1 convs -> rpn_score [16,1614] ----------------
__global__ void tidy_kernel(const float* __restrict__ d1, const float* __restrict__ d2,
                            const float* __restrict__ d3,
                            const float* __restrict__ w1, const float* __restrict__ b1,
                            const float* __restrict__ w2, const float* __restrict__ b2,
                            const float* __restrict__ w3, const float* __restrict__ b3,
                            float* __restrict__ score) {
  int i = blockIdx.x * 256 + threadIdx.x;
  if (i >= NB * NA) return;
  int b = i / NA, j = i - b * NA;
  float s;
  if (j < 1176) {
    int oc = j / 196, p = j - oc * 196;
    const float* in = d1 + (size_t)b * 128 * 196 + p;
    const float* w = w1 + oc * 128;
    s = b1[oc];
#pragma unroll 8
    for (int ic = 0; ic < 128; ic++) s += in[(size_t)ic * 196] * w[ic];
  } else if (j < 1470) {
    int jj = j - 1176;
    int oc = jj / 49, p = jj - oc * 49;
    const float* in = d2 + (size_t)b * 128 * 49 + p;
    const float* w = w2 + oc * 128;
    s = b2[oc];
#pragma unroll 8
    for (int ic = 0; ic < 128; ic++) s += in[(size_t)ic * 49] * w[ic];
  } else {
    int jj = j - 1470;
    int oc = jj / 16, p = jj & 15;
    const float* in = d3 + (size_t)b * 128 * 16 + p;
    const float* w = w3 + oc * 128;
    s = b3[oc];
#pragma unroll 8
    for (int ic = 0; ic < 128; ic++) s += in[(size_t)ic * 16] * w[ic];
  }
  score[i] = s;
}

// ---------------- NMS: per batch, TOPN=4, IoU>0.25 suppress ----------------
__global__ void nms_kernel(const float* __restrict__ score, const int* __restrict__ anchors,
                           float* __restrict__ out_idx, float* __restrict__ out_prob,
                           float* __restrict__ sel) {
  __shared__ float s_sc[NA];
  __shared__ float s_bx[NA * 4];
  __shared__ float r_s[256];
  __shared__ int r_i[256];
  const int b = blockIdx.x, tid = threadIdx.x;

  for (int i = tid; i < NA; i += 256) {
    s_sc[i] = score[b * NA + i];
    s_bx[i * 4 + 0] = (float)anchors[i * 4 + 0];
    s_bx[i * 4 + 1] = (float)anchors[i * 4 + 1];
    s_bx[i * 4 + 2] = (float)anchors[i * 4 + 2];
    s_bx[i * 4 + 3] = (float)anchors[i * 4 + 3];
  }
  __syncthreads();

  for (int t = 0; t < 4; t++) {
    float bs = -__builtin_inff();
    int bi = NA;
    for (int i = tid; i < NA; i += 256) {
      float s = s_sc[i];
      if (s > bs || (s == bs && i < bi)) { bs = s; bi = i; }
    }
    r_s[tid] = bs; r_i[tid] = bi;
    __syncthreads();
    for (int off = 128; off > 0; off >>= 1) {
      if (tid < off) {
        float s2 = r_s[tid + off]; int i2 = r_i[tid + off];
        if (s2 > r_s[tid] || (s2 == r_s[tid] && i2 < r_i[tid])) { r_s[tid] = s2; r_i[tid] = i2; }
      }
      __syncthreads();
    }
    const int idx = r_i[0];
    const float by0 = s_bx[idx * 4 + 0], bx0 = s_bx[idx * 4 + 1];
    const float by1 = s_bx[idx * 4 + 2], bx1 = s_bx[idx * 4 + 3];
    if (tid == 0) {
      out_idx[b * 4 + t] = (float)idx;
      out_prob[b * 4 + t] = s_sc[idx];
      sel[(b * 4 + t) * 4 + 0] = by0;
      sel[(b * 4 + t) * 4 + 1] = bx0;
      sel[(b * 4 + t) * 4 + 2] = by1;
      sel[(b * 4 + t) * 4 + 3] = bx1;
    }
    __syncthreads();
    const float a = (by1 - by0) * (bx1 - bx0);
    for (int i = tid; i < NA; i += 256) {
      float cy0 = s_bx[i * 4 + 0], cx0 = s_bx[i * 4 + 1];
      float cy1 = s_bx[i * 4 + 2], cx1 = s_bx[i * 4 + 3];
      float yy0 = fmaxf(by0, cy0), xx0 = fmaxf(bx0, cx0);
      float yy1 = fminf(by1, cy1), xx1 = fminf(bx1, cx1);
      float inter = fmaxf(yy1 - yy0, 0.f) * fmaxf(xx1 - xx0, 0.f);
      float ar = (cy1 - cy0) * (cx1 - cx0);
      float iou = inter / (a + ar - inter);
      if (iou > 0.25f) s_sc[i] = -__builtin_inff();
    }
    __syncthreads();
  }
}

// ---------------- crop+bilinear resize to [16,4,3,224,224] ----------------
__global__ void crop_kernel(const float* __restrict__ x, const float* __restrict__ sel,
                            float* __restrict__ out) {
  long long i = (long long)blockIdx.x * 256 + threadIdx.x;
  const long long total = (long long)NB * 4 * 3 * 224 * 224;
  if (i >= total) return;
  int px = (int)(i % 224);
  long long t = i / 224;
  int py = (int)(t % 224); t /= 224;
  int ch = (int)(t % 3);  t /= 3;
  int n  = (int)(t % 4);
  int b  = (int)(t / 4);

  const float* bx = sel + (b * 4 + n) * 4;
  const float y0 = bx[0], x0 = bx[1], y1 = bx[2], x1 = bx[3];

  float ty = (float)py / 223.0f;
  float cy = y0 + (y1 - 1.0f - y0) * ty;
  float cyf = floorf(cy);
  int ylo = (int)cyf; ylo = ylo < 0 ? 0 : (ylo > 895 ? 895 : ylo);
  int yhi = ylo + 1 > 895 ? 895 : ylo + 1;
  float wy = cy - cyf;

  float tx = (float)px / 223.0f;
  float cx = x0 + (x1 - 1.0f - x0) * tx;
  float cxf = floorf(cx);
  int xlo = (int)cxf; xlo = xlo < 0 ? 0 : (xlo > 895 ? 895 : xlo);
  int xhi = xlo + 1 > 895 ? 895 : xlo + 1;
  float wx = cx - cxf;

  const float* img = x + ((size_t)b * 3 + ch) * 448 * 448;
  auto g = [&](int yy, int xx) -> float {
    yy -= 224; xx -= 224;
    if ((unsigned)yy < 448u && (unsigned)xx < 448u)
      return img[(size_t)yy * 448 + xx];
    return 0.f;
  };
  float v00 = g(ylo, xlo), v01 = g(ylo, xhi);
  float v10 = g(yhi, xlo), v11 = g(yhi, xhi);
  float r = (1.f - wy) * ((1.f - wx) * v00 + wx * v01) +
            wy * ((1.f - wx) * v10 + wx * v11);
  out[i] = r;
}

extern "C" void kernel_launch(void* const* d_in, const int* in_sizes, int n_in,
                              void* d_out, int out_size, void* d_ws, size_t ws_size,
                              hipStream_t stream) {
  const float* x    = (const float*)d_in[0];
  const float* rpn  = (const float*)d_in[1];
  const int*   anc  = (const int*)d_in[2];
  const float* w_d1 = (const float*)d_in[3];
  const float* b_d1 = (const float*)d_in[4];
  const float* w_d2 = (const float*)d_in[5];
  const float* b_d2 = (const float*)d_in[6];
  const float* w_d3 = (const float*)d_in[7];
  const float* b_d3 = (const float*)d_in[8];
  const float* w_t1 = (const float*)d_in[9];
  const float* b_t1 = (const float*)d_in[10];
  const float* w_t2 = (const float*)d_in[11];
  const float* b_t2 = (const float*)d_in[12];
  const float* w_t3 = (const float*)d_in[13];
  const float* b_t3 = (const float*)d_in[14];

  float* out = (float*)d_out;
  float* ws = (float*)d_ws;

  float* d1  = ws;                        // 401408
  float* d2  = d1 + 401408;               // 100352
  float* d3  = d2 + 100352;               // 32768
  float* sel = d3 + 32768;                // 256
  float* p2  = sel + 256;                 // 401408
  float* p3  = p2 + 401408;               // 65536
  unsigned short* wTh = (unsigned short*)(p3 + 65536);   // 2,359,296 ush
  unsigned short* wTl = wTh + 2359296;                   // 2,359,296 ush
  float* p1  = (float*)(wTl + 2359296);   // 6,422,528 floats (partials mode only)

  const size_t need_partials =
      (size_t)(401408 + 100352 + 32768 + 256 + 401408 + 65536 + 6422528) * 4 +
      (size_t)2 * 2359296 * 2;
  const int atomic_mode = (ws_size >= need_partials) ? 0 : 1;

  float* score    = out;                  // 25824
  float* out_idx  = out + 25824;          // 64
  float* out_prob = out + 25888;          // 64
  float* parts    = out + 25952;          // 9,633,792

  prep_w<<<dim3(9216), dim3(256), 0, stream>>>(w_d1, wTh, wTl);
  if (atomic_mode) {
    hipMemsetAsync(d1, 0, (size_t)NB * 128 * 196 * sizeof(float), stream);
    conv1_mfma<<<dim3(512), dim3(256), 0, stream>>>(rpn, wTh, wTl, d1, 1);
    conv1_finish_a<<<dim3(1568), dim3(256), 0, stream>>>(d1, b_d1);
  } else {
    conv1_mfma<<<dim3(512), dim3(256), 0, stream>>>(rpn, wTh, wTl, p1, 0);
    conv1_finish_p<<<dim3(1568), dim3(256), 0, stream>>>(p1, b_d1, d1);
  }
  conv2_part<<<dim3(256), dim3(256), 0, stream>>>(d1, w_d2, p2);
  conv2_finish<<<dim3(392), dim3(256), 0, stream>>>(p2, b_d2, d2);
  conv3_part<<<dim3(256), dim3(256), 0, stream>>>(d2, w_d3, p3);
  conv3_finish<<<dim3(128), dim3(256), 0, stream>>>(p3, b_d3, d3);
  tidy_kernel<<<dim3(101), dim3(256), 0, stream>>>(d1, d2, d3, w_t1, b_t1, w_t2, b_t2,
                                                   w_t3, b_t3, score);
  nms_kernel<<<dim3(16), dim3(256), 0, stream>>>(score, anc, out_idx, out_prob, sel);
  crop_kernel<<<dim3(37632), dim3(256), 0, stream>>>(x, sel, parts);
}

// Round 6
// 299.597 us; speedup vs baseline: 2.0459x; 1.0236x over previous
//
#include <hip/hip_runtime.h>
#include <hip/hip_bf16.h>

#define NB 16
#define NA 1614

typedef __bf16 bf16x8 __attribute__((ext_vector_type(8)));
typedef float f32x4 __attribute__((ext_vector_type(4)));

__device__ __forceinline__ unsigned short f2bf(float v) {
  unsigned u = __float_as_uint(v);
  unsigned r = (u + 0x7FFFu + ((u >> 16) & 1u)) >> 16;
  return (unsigned short)r;
}
__device__ __forceinline__ float bf2f(unsigned short s) {
  return __uint_as_float(((unsigned)s) << 16);
}

// ---------------- prep_w: w[128][2048][9] f32 -> wTh/wTl [9][128][2048] bf16 hi/lo ----------
__global__ void prep_w(const float* __restrict__ w, unsigned short* __restrict__ wTh,
                       unsigned short* __restrict__ wTl) {
  int e = blockIdx.x * 256 + threadIdx.x;
  if (e >= 9 * 128 * 2048) return;
  int tap = e / (128 * 2048);
  int rem = e - tap * (128 * 2048);
  int oc = rem >> 11, ic = rem & 2047;
  float v = w[((size_t)oc * 2048 + ic) * 9 + tap];
  unsigned short h = f2bf(v);
  wTh[e] = h;
  wTl[e] = f2bf(v - bf2f(h));
}

// ---------------- prep_a: rpn [16,2048,196] f32 -> aTh/aTl [b][chunk64][pos196][ic32] ------
// LDS-tiled transpose + hi/lo split, coalesced on both sides.
__global__ __launch_bounds__(256)
void prep_a(const float* __restrict__ in, unsigned short* __restrict__ aTh,
            unsigned short* __restrict__ aTl) {
  const int bid = blockIdx.x;            // 1024 = 16 b x 64 chunks
  const int chunk = bid & 63, b = bid >> 6;
  __shared__ float s[32 * 200];
  const float* src = in + ((size_t)b * 2048 + chunk * 32) * 196;
#pragma unroll
  for (int r = 0; r < 7; r++) {
    int e = threadIdx.x + 256 * r;       // float4 units, 1568 total
    if (e < 1568) {
      int ic = e / 49, f = e - ic * 49;
      float4 v = ((const float4*)(src + (size_t)ic * 196))[f];
      *(float4*)(s + ic * 200 + f * 4) = v;
    }
  }
  __syncthreads();
  unsigned short* oh = aTh + (size_t)bid * 196 * 32;
  unsigned short* ol = aTl + (size_t)bid * 196 * 32;
#pragma unroll
  for (int r = 0; r < 4; r++) {
    int e = threadIdx.x + 256 * r;       // bf16x8 units, 784 total
    if (e < 784) {
      int g = e / 196, pos = e - g * 196;
      unsigned short hv[8], lv[8];
#pragma unroll
      for (int j = 0; j < 8; j++) {
        float v = s[(g * 8 + j) * 200 + pos];
        unsigned short h = f2bf(v);
        hv[j] = h;
        lv[j] = f2bf(v - bf2f(h));
      }
      *(uint4*)(oh + (size_t)pos * 32 + g * 8) = *(uint4*)hv;
      *(uint4*)(ol + (size_t)pos * 32 + g * 8) = *(uint4*)lv;
    }
  }
}

// ---------------- conv1 MFMA: implicit GEMM, split-bf16, partials to p1 ----------------
// grid 512 = kc(16, 128-ic) x nh(2, 64-oc) x b(16). Block: M=196 x N=64, 4 waves (7mf x 2nf).
// A copied from pre-transposed aT (8 uint4/thread per 32-ic stage); B register-prefetched.
__global__ __launch_bounds__(256, 3)
void conv1_mfma(const unsigned short* __restrict__ aTh, const unsigned short* __restrict__ aTl,
                const unsigned short* __restrict__ wTh, const unsigned short* __restrict__ wTl,
                float* __restrict__ p1) {
  const int bid = blockIdx.x;
  const int b  = bid & 15;
  const int nh = (bid >> 4) & 1;
  const int kc = bid >> 5;
  const int tid = threadIdx.x;
  const int wid = tid >> 6, lane = tid & 63;
  const int wm = wid & 1, wn = wid >> 1;
  const int q = lane >> 4, ln = lane & 15;

  __shared__ unsigned short sAh[256 * 40];   // [pospad256][ic32 +8pad]
  __shared__ unsigned short sAl[256 * 40];
  __shared__ unsigned short sBh[64 * 40];    // [oc64][ic32 +8pad]
  __shared__ unsigned short sBl[64 * 40];

  // zero once: borders & pad stay zero forever (stages overwrite interior only)
  for (int e = tid; e < 5120; e += 256) {
    ((unsigned int*)sAh)[e] = 0u;
    ((unsigned int*)sAl)[e] = 0u;
  }

  int abase[7];
#pragma unroll
  for (int mf = 0; mf < 7; mf++) {
    int row = wm * 112 + mf * 16 + ln;
    int y = row / 14, x = row - y * 14;
    abase[mf] = ((row < 196) ? (y * 16 + x) : 0) * 40 + q * 8;
  }

  f32x4 acc[7][2];
#pragma unroll
  for (int mf = 0; mf < 7; mf++)
#pragma unroll
    for (int nf = 0; nf < 2; nf++) acc[mf][nf] = (f32x4){0.f, 0.f, 0.f, 0.f};

  // B staging map: thread -> (oc 0..63, icl0)
  const int boc = tid >> 2, bic0 = (tid & 3) * 8;
  const size_t bocbase = (size_t)(nh * 64 + boc) << 11;

  uint4 pvh, pvl;
  {
    size_t g = bocbase + kc * 128 + bic0;   // tap=0, ks=0
    pvh = *(const uint4*)(wTh + g);
    pvl = *(const uint4*)(wTl + g);
  }

  for (int it = 0; it < 36; it++) {
    const int ks = it / 9, tap = it - ks * 9;
    __syncthreads();
    *(uint4*)(sBh + boc * 40 + bic0) = pvh;
    *(uint4*)(sBl + boc * 40 + bic0) = pvl;
    if (tap == 0) {
      const uint4* gh = (const uint4*)(aTh + ((size_t)(b * 64 + kc * 4 + ks) * 196) * 32);
      const uint4* gl = (const uint4*)(aTl + ((size_t)(b * 64 + kc * 4 + ks) * 196) * 32);
#pragma unroll
      for (int r = 0; r < 4; r++) {
        int e = tid + 256 * r;               // uint4 units, 784 = 196 pos x 4
        if (e < 784) {
          int slot = e >> 2, part = e & 3;
          int py = slot / 14, px = slot - py * 14;
          int dst = ((py + 1) * 16 + px + 1) * 40 + part * 8;
          *(uint4*)(sAh + dst) = gh[e];
          *(uint4*)(sAl + dst) = gl[e];
        }
      }
    }
    // prefetch next tap's B
    {
      const int nit = (it < 35) ? it + 1 : 35;
      const int ks2 = nit / 9, tap2 = nit - ks2 * 9;
      size_t g = (size_t)tap2 * (128 * 2048) + bocbase + kc * 128 + ks2 * 32 + bic0;
      pvh = *(const uint4*)(wTh + g);
      pvl = *(const uint4*)(wTl + g);
    }
    __syncthreads();

    const int t40 = ((tap / 3) * 16 + (tap % 3)) * 40;
    bf16x8 bh[2], bl[2];
#pragma unroll
    for (int nf = 0; nf < 2; nf++) {
      const int bb = (wn * 32 + nf * 16 + ln) * 40 + q * 8;
      bh[nf] = *(const bf16x8*)(sBh + bb);
      bl[nf] = *(const bf16x8*)(sBl + bb);
    }
#pragma unroll
    for (int mf = 0; mf < 7; mf++) {
      bf16x8 ah = *(const bf16x8*)(sAh + abase[mf] + t40);
      bf16x8 al = *(const bf16x8*)(sAl + abase[mf] + t40);
#pragma unroll
      for (int nf = 0; nf < 2; nf++) {
        acc[mf][nf] = __builtin_amdgcn_mfma_f32_16x16x32_bf16(ah, bh[nf], acc[mf][nf], 0, 0, 0);
        acc[mf][nf] = __builtin_amdgcn_mfma_f32_16x16x32_bf16(al, bh[nf], acc[mf][nf], 0, 0, 0);
        acc[mf][nf] = __builtin_amdgcn_mfma_f32_16x16x32_bf16(ah, bl[nf], acc[mf][nf], 0, 0, 0);
      }
    }
  }

  // p1[kc][b][pos196][oc128], coalesced 64B segments
  float* pk = p1 + ((size_t)kc * NB + b) * 196 * 128;
#pragma unroll
  for (int mf = 0; mf < 7; mf++) {
    const int row0 = wm * 112 + mf * 16 + q * 4;
#pragma unroll
    for (int nf = 0; nf < 2; nf++) {
      const int oc = nh * 64 + wn * 32 + nf * 16 + ln;
#pragma unroll
      for (int r = 0; r < 4; r++) {
        const int row = row0 + r;
        if (row < 196) pk[(size_t)row * 128 + oc] = acc[mf][nf][r];
      }
    }
  }
}

// finish: sum 16 kc slabs + bias + relu, transpose to [b][oc][pos]
__global__ void conv1_finish_p(const float* __restrict__ p1, const float* __restrict__ bias,
                               float* __restrict__ d1) {
  const int i = blockIdx.x * 256 + threadIdx.x;
  if (i >= NB * 196 * 128) return;
  const int oc = i & 127;
  const int t = i >> 7;
  const int pos = t % 196, b = t / 196;
  float s = bias[oc];
#pragma unroll
  for (int k = 0; k < 16; k++) s += p1[(size_t)k * (NB * 196 * 128) + i];
  d1[((size_t)b * 128 + oc) * 196 + pos] = fmaxf(s, 0.f);
}

// ---------------- conv2: d1 [16,128,14,14] -> partials, stride2 pad1 ----------------
__global__ void conv2_part(const float* __restrict__ d1, const float* __restrict__ w,
                           float* __restrict__ p2) {
  const int bid = blockIdx.x;
  const int kc = bid & 3, oct = (bid >> 2) & 3, b = bid >> 4;
  const int ic0 = kc * 32, oc0 = oct * 32;
  const int tid = threadIdx.x;
  const int ocl = tid >> 3, rw = tid & 7;

  __shared__ float s_in[32 * 320];
  __shared__ float s_w[32 * 324];

#pragma unroll
  for (int r = 0; r < 32; r++) {
    const int e = tid + 256 * r;
    const int ch = e >> 8, idx = e & 255;
    const int tr = idx >> 4, tc = idx & 15;
    const int iy = tr - 1, ix = tc - 1;
    float v = 0.f;
    if ((unsigned)iy < 14u && (unsigned)ix < 14u)
      v = d1[((size_t)b * 128 + ic0 + ch) * 196 + iy * 14 + ix];
    s_in[ch * 320 + tr * 20 + tc] = v;
  }
#pragma unroll
  for (int r = 0; r < 36; r++) {
    const int e = tid + 256 * r;
    const int oc = e / 288, rem = e - oc * 288;
    const int ch = rem / 9, tap = rem - ch * 9;
    s_w[ch * 324 + tap * 36 + oc] =
        w[(size_t)(oc0 + oc) * 1152 + (size_t)ic0 * 9 + rem];
  }
  __syncthreads();

  if (rw < 7) {
    float acc[7] = {};
    for (int ic = 0; ic < 32; ic++) {
      const float* wrow = s_w + ic * 324 + ocl;
      const float* irow = s_in + ic * 320;
#pragma unroll
      for (int ky = 0; ky < 3; ky++) {
        const float* r = irow + (2 * rw + ky) * 20;
        const float4 f0 = *(const float4*)(r);
        const float4 f1 = *(const float4*)(r + 4);
        const float4 f2 = *(const float4*)(r + 8);
        const float4 f3 = *(const float4*)(r + 12);
        const float ev[8] = {f0.x, f0.z, f1.x, f1.z, f2.x, f2.z, f3.x, f3.z};
        const float od[7] = {f0.y, f0.w, f1.y, f1.w, f2.y, f2.w, f3.y};
        const float w0 = wrow[(ky * 3 + 0) * 36];
        const float w1 = wrow[(ky * 3 + 1) * 36];
        const float w2 = wrow[(ky * 3 + 2) * 36];
#pragma unroll
        for (int x = 0; x < 7; x++)
          acc[x] = fmaf(w0, ev[x], fmaf(w1, od[x], fmaf(w2, ev[x + 1], acc[x])));
      }
    }
    float* po = p2 + (((size_t)kc * NB + b) * 128 + oc0 + ocl) * 49 + rw * 7;
#pragma unroll
    for (int x = 0; x < 7; x++) po[x] = acc[x];
  }
}

__global__ void conv2_finish(const float* __restrict__ p2, const float* __restrict__ bias,
                             float* __restrict__ d2) {
  const int i = blockIdx.x * 256 + threadIdx.x;
  if (i >= NB * 128 * 49) return;
  const int oc = (i / 49) & 127;
  float s = bias[oc];
#pragma unroll
  for (int k = 0; k < 4; k++) s += p2[(size_t)k * (NB * 128 * 49) + i];
  d2[i] = fmaxf(s, 0.f);
}

// ---------------- conv3: d2 [16,128,7,7] -> partials, stride2 pad1 ----------------
__global__ void conv3_part(const float* __restrict__ d2, const float* __restrict__ w,
                           float* __restrict__ p3) {
  const int bid = blockIdx.x;
  const int kc = bid & 1, oct = (bid >> 1) & 7, b = bid >> 4;
  const int ic0 = kc * 64, oc0 = oct * 16;
  const int tid = threadIdx.x;
  const int oc = tid >> 4, p = tid & 15;
  const int y = p >> 2, x = p & 3;

  __shared__ float s_in[64 * 108];
  __shared__ float s_w[64 * 144];

#pragma unroll
  for (int r = 0; r < 21; r++) {
    const int e = tid + 256 * r;
    if (e < 64 * 81) {
      const int ch = e / 81, idx = e - ch * 81;
      const int tr = idx / 9, tc = idx - tr * 9;
      const int iy = tr - 1, ix = tc - 1;
      float v = 0.f;
      if ((unsigned)iy < 7u && (unsigned)ix < 7u)
        v = d2[((size_t)b * 128 + ic0 + ch) * 49 + iy * 7 + ix];
      s_in[ch * 108 + tr * 12 + tc] = v;
    }
  }
#pragma unroll
  for (int r = 0; r < 36; r++) {
    const int e = tid + 256 * r;
    const int o = e / 576, rem = e - o * 576;
    const int ch = rem / 9, tap = rem - ch * 9;
    s_w[ch * 144 + tap * 16 + o] =
        w[(size_t)(oc0 + o) * 1152 + (size_t)ic0 * 9 + rem];
  }
  __syncthreads();

  float acc = 0.f;
  for (int ic = 0; ic < 64; ic++) {
    const float* wrow = s_w + ic * 144 + oc;
    const float* irow = s_in + ic * 108 + 2 * y * 12 + 2 * x;
#pragma unroll
    for (int ky = 0; ky < 3; ky++)
#pragma unroll
      for (int kx = 0; kx < 3; kx++)
        acc = fmaf(wrow[(ky * 3 + kx) * 16], irow[ky * 12 + kx], acc);
  }
  p3[(((size_t)kc * NB + b) * 128 + oc0 + oc) * 16 + p] = acc;
}

__global__ void conv3_finish(const float* __restrict__ p3, const float* __restrict__ bias,
                             float* __restrict__ d3) {
  const int i = blockIdx.x * 256 + threadIdx.x;
  if (i >= NB * 128 * 16) return;
  const int oc = (i >> 4) & 127;
  float s = bias[oc] + p3[i] + p3[(size_t)(NB * 128 * 16) + i];
  d3[i] = fmaxf(s, 0.f);
}

// ---------------- fused tidy(1x1 convs) + NMS, one block per batch ----------------
__global__ __launch_bounds__(256, 1)
void score_nms(const float* __restrict__ d1, const float* __restrict__ d2,
               const float* __restrict__ d3,
               const float* __restrict__ w1, const float* __restrict__ b1,
               const float* __restrict__ w2, const float* __restrict__ b2,
               const float* __restrict__ w3, const float* __restrict__ b3,
               const int* __restrict__ anchors, float* __restrict__ score,
               float* __restrict__ out_idx, float* __restrict__ out_prob,
               float* __restrict__ sel) {
  __shared__ float s_in[32 * 200];     // t1 chunks; reused linearly for d2 (6272) / d3 (2048)
  __shared__ float s_w[21 * 128];      // w1(0..5), w2(6..11), w3(12..20)
  __shared__ float s_b[21];
  __shared__ float s_sc[NA];
  __shared__ float s_bx[NA * 4];
  __shared__ float r_s[256];
  __shared__ int r_i[256];
  const int b = blockIdx.x, tid = threadIdx.x;

  for (int i = tid; i < 768; i += 256) s_w[i] = w1[i];
  for (int i = tid; i < 768; i += 256) s_w[768 + i] = w2[i];
  for (int i = tid; i < 1152; i += 256) s_w[1536 + i] = w3[i];
  if (tid < 21) s_b[tid] = (tid < 6) ? b1[tid] : (tid < 12) ? b2[tid - 6] : b3[tid - 12];
  for (int i = tid; i < NA; i += 256) {
    s_bx[i * 4 + 0] = (float)anchors[i * 4 + 0];
    s_bx[i * 4 + 1] = (float)anchors[i * 4 + 1];
    s_bx[i * 4 + 2] = (float)anchors[i * 4 + 2];
    s_bx[i * 4 + 3] = (float)anchors[i * 4 + 3];
  }

  // ---- t1: 6 oc x 196 pos = 1176 scores, d1 staged in 4 chunks of 32 ic ----
  float acc[5] = {0.f, 0.f, 0.f, 0.f, 0.f};
  for (int chunk = 0; chunk < 4; chunk++) {
    __syncthreads();
    const float* src = d1 + ((size_t)b * 128 + chunk * 32) * 196;
#pragma unroll
    for (int r = 0; r < 7; r++) {
      int e = tid + 256 * r;
      if (e < 1568) {
        int ic = e / 49, f = e - ic * 49;
        *(float4*)(s_in + ic * 200 + f * 4) = ((const float4*)(src + (size_t)ic * 196))[f];
      }
    }
    __syncthreads();
#pragma unroll
    for (int k = 0; k < 5; k++) {
      int j = tid + 256 * k;
      if (j < 1176) {
        int oc = j / 196, p = j - oc * 196;
        const float* wr = s_w + oc * 128 + chunk * 32;
        float s = acc[k];
#pragma unroll
        for (int ic = 0; ic < 32; ic++) s = fmaf(wr[ic], s_in[ic * 200 + p], s);
        acc[k] = s;
      }
    }
  }
#pragma unroll
  for (int k = 0; k < 5; k++) {
    int j = tid + 256 * k;
    if (j < 1176) {
      int oc = j / 196;
      float s = acc[k] + s_b[oc];
      s_sc[j] = s;
      score[b * NA + j] = s;
    }
  }

  // ---- t2: 6 oc x 49 = 294 scores, d2[b] staged fully (linear) ----
  __syncthreads();
  {
    const float* src = d2 + (size_t)b * 6272;
#pragma unroll
    for (int r = 0; r < 7; r++) {
      int e = tid + 256 * r;
      if (e < 1568) *(float4*)(s_in + e * 4) = ((const float4*)src)[e];
    }
  }
  __syncthreads();
#pragma unroll
  for (int k = 0; k < 2; k++) {
    int jj = tid + 256 * k;
    if (jj < 294) {
      int oc = jj / 49, p = jj - oc * 49;
      const float* wr = s_w + 768 + oc * 128;
      float s = s_b[6 + oc];
#pragma unroll 8
      for (int ic = 0; ic < 128; ic++) s = fmaf(wr[ic], s_in[ic * 49 + p], s);
      s_sc[1176 + jj] = s;
      score[b * NA + 1176 + jj] = s;
    }
  }

  // ---- t3: 9 oc x 16 = 144 scores ----
  __syncthreads();
  {
    const float* src = d3 + (size_t)b * 2048;
#pragma unroll
    for (int r = 0; r < 2; r++) {
      int e = tid + 256 * r;
      if (e < 512) *(float4*)(s_in + e * 4) = ((const float4*)src)[e];
    }
  }
  __syncthreads();
  if (tid < 144) {
    int oc = tid >> 4, p = tid & 15;
    const float* wr = s_w + 1536 + oc * 128;
    float s = s_b[12 + oc];
#pragma unroll 8
    for (int ic = 0; ic < 128; ic++) s = fmaf(wr[ic], s_in[ic * 16 + p], s);
    s_sc[1470 + tid] = s;
    score[b * NA + 1470 + tid] = s;
  }
  __syncthreads();

  // ---- NMS: TOPN=4, IoU>0.25 suppress ----
  for (int t = 0; t < 4; t++) {
    float bs = -__builtin_inff();
    int bi = NA;
    for (int i = tid; i < NA; i += 256) {
      float s = s_sc[i];
      if (s > bs || (s == bs && i < bi)) { bs = s; bi = i; }
    }
    r_s[tid] = bs; r_i[tid] = bi;
    __syncthreads();
    for (int off = 128; off > 0; off >>= 1) {
      if (tid < off) {
        float s2 = r_s[tid + off]; int i2 = r_i[tid + off];
        if (s2 > r_s[tid] || (s2 == r_s[tid] && i2 < r_i[tid])) { r_s[tid] = s2; r_i[tid] = i2; }
      }
      __syncthreads();
    }
    const int idx = r_i[0];
    const float by0 = s_bx[idx * 4 + 0], bx0 = s_bx[idx * 4 + 1];
    const float by1 = s_bx[idx * 4 + 2], bx1 = s_bx[idx * 4 + 3];
    if (tid == 0) {
      out_idx[b * 4 + t] = (float)idx;
      out_prob[b * 4 + t] = s_sc[idx];
      sel[(b * 4 + t) * 4 + 0] = by0;
      sel[(b * 4 + t) * 4 + 1] = bx0;
      sel[(b * 4 + t) * 4 + 2] = by1;
      sel[(b * 4 + t) * 4 + 3] = bx1;
    }
    __syncthreads();
    const float a = (by1 - by0) * (bx1 - bx0);
    for (int i = tid; i < NA; i += 256) {
      float cy0 = s_bx[i * 4 + 0], cx0 = s_bx[i * 4 + 1];
      float cy1 = s_bx[i * 4 + 2], cx1 = s_bx[i * 4 + 3];
      float yy0 = fmaxf(by0, cy0), xx0 = fmaxf(bx0, cx0);
      float yy1 = fminf(by1, cy1), xx1 = fminf(bx1, cx1);
      float inter = fmaxf(yy1 - yy0, 0.f) * fmaxf(xx1 - xx0, 0.f);
      float ar = (cy1 - cy0) * (cx1 - cx0);
      float iou = inter / (a + ar - inter);
      if (iou > 0.25f) s_sc[i] = -__builtin_inff();
    }
    __syncthreads();
  }
}

// ---------------- crop+bilinear resize to [16,4,3,224,224] ----------------
__global__ void crop_kernel(const float* __restrict__ x, const float* __restrict__ sel,
                            float* __restrict__ out) {
  long long i = (long long)blockIdx.x * 256 + threadIdx.x;
  const long long total = (long long)NB * 4 * 3 * 224 * 224;
  if (i >= total) return;
  int px = (int)(i % 224);
  long long t = i / 224;
  int py = (int)(t % 224); t /= 224;
  int ch = (int)(t % 3);  t /= 3;
  int n  = (int)(t % 4);
  int b  = (int)(t / 4);

  const float* bx = sel + (b * 4 + n) * 4;
  const float y0 = bx[0], x0 = bx[1], y1 = bx[2], x1 = bx[3];

  float ty = (float)py / 223.0f;
  float cy = y0 + (y1 - 1.0f - y0) * ty;
  float cyf = floorf(cy);
  int ylo = (int)cyf; ylo = ylo < 0 ? 0 : (ylo > 895 ? 895 : ylo);
  int yhi = ylo + 1 > 895 ? 895 : ylo + 1;
  float wy = cy - cyf;

  float tx = (float)px / 223.0f;
  float cx = x0 + (x1 - 1.0f - x0) * tx;
  float cxf = floorf(cx);
  int xlo = (int)cxf; xlo = xlo < 0 ? 0 : (xlo > 895 ? 895 : xlo);
  int xhi = xlo + 1 > 895 ? 895 : xlo + 1;
  float wx = cx - cxf;

  const float* img = x + ((size_t)b * 3 + ch) * 448 * 448;
  auto g = [&](int yy, int xx) -> float {
    yy -= 224; xx -= 224;
    if ((unsigned)yy < 448u && (unsigned)xx < 448u)
      return img[(size_t)yy * 448 + xx];
    return 0.f;
  };
  float v00 = g(ylo, xlo), v01 = g(ylo, xhi);
  float v10 = g(yhi, xlo), v11 = g(yhi, xhi);
  float r = (1.f - wy) * ((1.f - wx) * v00 + wx * v01) +
            wy * ((1.f - wx) * v10 + wx * v11);
  out[i] = r;
}

extern "C" void kernel_launch(void* const* d_in, const int* in_sizes, int n_in,
                              void* d_out, int out_size, void* d_ws, size_t ws_size,
                              hipStream_t stream) {
  const float* x    = (const float*)d_in[0];
  const float* rpn  = (const float*)d_in[1];
  const int*   anc  = (const int*)d_in[2];
  const float* w_d1 = (const float*)d_in[3];
  const float* b_d1 = (const float*)d_in[4];
  const float* w_d2 = (const float*)d_in[5];
  const float* b_d2 = (const float*)d_in[6];
  const float* w_d3 = (const float*)d_in[7];
  const float* b_d3 = (const float*)d_in[8];
  const float* w_t1 = (const float*)d_in[9];
  const float* b_t1 = (const float*)d_in[10];
  const float* w_t2 = (const float*)d_in[11];
  const float* b_t2 = (const float*)d_in[12];
  const float* w_t3 = (const float*)d_in[13];
  const float* b_t3 = (const float*)d_in[14];

  float* out = (float*)d_out;
  float* ws = (float*)d_ws;

  float* d1  = ws;                        // 401408
  float* d2  = d1 + 401408;               // 100352
  float* d3  = d2 + 100352;               // 32768
  float* sel = d3 + 32768;                // 256
  float* p2  = sel + 256;                 // 401408
  float* p3  = p2 + 401408;               // 65536
  unsigned short* wTh = (unsigned short*)(p3 + 65536);   // 2,359,296 ush
  unsigned short* wTl = wTh + 2359296;                   // 2,359,296 ush
  unsigned short* aTh = wTl + 2359296;                   // 6,422,528 ush
  unsigned short* aTl = aTh + 6422528;                   // 6,422,528 ush
  // total ws need: 39,134,208 B (same as round 5's verified-working partials layout)

  float* score    = out;                  // 25824
  float* out_idx  = out + 25824;          // 64
  float* out_prob = out + 25888;          // 64
  float* parts    = out + 25952;          // 9,633,792 (final crop output)
  float* p1       = parts;                // 6,422,528 floats scratch; crop overwrites after

  prep_w<<<dim3(9216), dim3(256), 0, stream>>>(w_d1, wTh, wTl);
  prep_a<<<dim3(1024), dim3(256), 0, stream>>>(rpn, aTh, aTl);
  conv1_mfma<<<dim3(512), dim3(256), 0, stream>>>(aTh, aTl, wTh, wTl, p1);
  conv1_finish_p<<<dim3(1568), dim3(256), 0, stream>>>(p1, b_d1, d1);
  conv2_part<<<dim3(256), dim3(256), 0, stream>>>(d1, w_d2, p2);
  conv2_finish<<<dim3(392), dim3(256), 0, stream>>>(p2, b_d2, d2);
  conv3_part<<<dim3(256), dim3(256), 0, stream>>>(d2, w_d3, p3);
  conv3_finish<<<dim3(128), dim3(256), 0, stream>>>(p3, b_d3, d3);
  score_nms<<<dim3(16), dim3(256), 0, stream>>>(d1, d2, d3, w_t1, b_t1, w_t2, b_t2,
                                                w_t3, b_t3, anc, score, out_idx, out_prob, sel);
  crop_kernel<<<dim3(37632), dim3(256), 0, stream>>>(x, sel, parts);
}

// Round 7
// 282.235 us; speedup vs baseline: 2.1718x; 1.0615x over previous
//
#include <hip/hip_runtime.h>
#include <hip/hip_bf16.h>

#define NB 16
#define NA 1614
#define NBP (NB * 196 * 128)   // p1 slab stride = 401408

typedef __bf16 bf16x8 __attribute__((ext_vector_type(8)));
typedef float f32x4 __attribute__((ext_vector_type(4)));

__device__ __forceinline__ unsigned short f2bf(float v) {
  unsigned u = __float_as_uint(v);
  unsigned r = (u + 0x7FFFu + ((u >> 16) & 1u)) >> 16;
  return (unsigned short)r;
}
__device__ __forceinline__ float bf2f(unsigned short s) {
  return __uint_as_float(((unsigned)s) << 16);
}

// ---------------- prep (fused): blocks [0,1024) transpose+split rpn -> aT; rest -> wT ------
// aT layout: [chunk = b*64 + ic32grp][pos196][ic32] hi/lo, written fully coalesced (pos-major).
__global__ __launch_bounds__(256)
void prep(const float* __restrict__ w, const float* __restrict__ in,
          unsigned short* __restrict__ wTh, unsigned short* __restrict__ wTl,
          unsigned short* __restrict__ aTh, unsigned short* __restrict__ aTl) {
  __shared__ float s[32 * 201];
  const int bid = blockIdx.x;
  if (bid < 1024) {
    const int chunk = bid & 63, b = bid >> 6;
    const float* src = in + ((size_t)b * 2048 + chunk * 32) * 196;
#pragma unroll
    for (int r = 0; r < 7; r++) {
      int e = threadIdx.x + 256 * r;
      if (e < 1568) {
        int ic = e / 49, f = e - ic * 49;
        float4 v = ((const float4*)(src + (size_t)ic * 196))[f];
        float* d = s + ic * 201 + f * 4;
        d[0] = v.x; d[1] = v.y; d[2] = v.z; d[3] = v.w;
      }
    }
    __syncthreads();
    unsigned short* oh = aTh + (size_t)bid * (196 * 32);
    unsigned short* ol = aTl + (size_t)bid * (196 * 32);
#pragma unroll
    for (int r = 0; r < 4; r++) {
      int e = threadIdx.x + 256 * r;   // uint4 units; e = pos*4 + part -> contiguous writes
      if (e < 784) {
        int pos = e >> 2, part = e & 3;
        unsigned short hv[8], lv[8];
#pragma unroll
        for (int j = 0; j < 8; j++) {
          float v = s[(part * 8 + j) * 201 + pos];
          unsigned short h = f2bf(v);
          hv[j] = h;
          lv[j] = f2bf(v - bf2f(h));
        }
        ((uint4*)oh)[e] = *(uint4*)hv;
        ((uint4*)ol)[e] = *(uint4*)lv;
      }
    }
  } else {
    int e = (bid - 1024) * 256 + threadIdx.x;
    if (e < 9 * 128 * 2048) {
      int tap = e / (128 * 2048);
      int rem = e - tap * (128 * 2048);
      int oc = rem >> 11, ic = rem & 2047;
      float v = w[((size_t)oc * 2048 + ic) * 9 + tap];
      unsigned short h = f2bf(v);
      wTh[e] = h;
      wTl[e] = f2bf(v - bf2f(h));
    }
  }
}

// ---------------- conv1 MFMA: implicit GEMM, split-bf16, plane-split LDS ----------------
// grid 512 = kc(16) x nh(2) x b(16). Block: M=196 x N=64, 4 waves (7mf x 2nf).
// LDS planes [icq4][pos/oc][8ic] -> all b128 accesses bank-balanced (16B/pos pitch).
__global__ __launch_bounds__(256, 3)
void conv1_mfma(const unsigned short* __restrict__ aTh, const unsigned short* __restrict__ aTl,
                const unsigned short* __restrict__ wTh, const unsigned short* __restrict__ wTl,
                float* __restrict__ p1) {
  const int bid = blockIdx.x;
  const int b  = bid & 15;
  const int nh = (bid >> 4) & 1;
  const int kc = bid >> 5;
  const int tid = threadIdx.x;
  const int wid = tid >> 6, lane = tid & 63;
  const int wm = wid & 1, wn = wid >> 1;
  const int q = lane >> 4, ln = lane & 15;

  __shared__ unsigned short sAh[4 * 2048];   // [icq4][pospad256][8]
  __shared__ unsigned short sAl[4 * 2048];
  __shared__ unsigned short sBh[4 * 512];    // [icq4][oc64][8]
  __shared__ unsigned short sBl[4 * 512];

  // zero A once: padded-grid borders stay zero (stages overwrite interior only)
  for (int e = tid; e < 4096; e += 256) {
    ((unsigned int*)sAh)[e] = 0u;
    ((unsigned int*)sAl)[e] = 0u;
  }

  int abase[7];
#pragma unroll
  for (int mf = 0; mf < 7; mf++) {
    int row = wm * 112 + mf * 16 + ln;
    int y = row / 14, x = row - y * 14;
    abase[mf] = ((row < 196) ? (y * 16 + x) : 0) * 8;
  }
  const int qoff = q * 2048;

  f32x4 acc[7][2];
#pragma unroll
  for (int mf = 0; mf < 7; mf++)
#pragma unroll
    for (int nf = 0; nf < 2; nf++) acc[mf][nf] = (f32x4){0.f, 0.f, 0.f, 0.f};

  // B staging map: thread -> (oc = tid>>2, icq = tid&3)
  const int boc = tid >> 2, bicq = tid & 3;
  const size_t bocbase = (size_t)(nh * 64 + boc) << 11;

  uint4 pvh, pvl;
  {
    size_t g = bocbase + kc * 128 + bicq * 8;   // tap=0, ks=0
    pvh = *(const uint4*)(wTh + g);
    pvl = *(const uint4*)(wTl + g);
  }

  for (int it = 0; it < 36; it++) {
    const int ks = it / 9, tap = it - ks * 9;
    __syncthreads();
    *(uint4*)(sBh + bicq * 512 + boc * 8) = pvh;
    *(uint4*)(sBl + bicq * 512 + boc * 8) = pvl;
    if (tap == 0) {
      const uint4* gh = (const uint4*)(aTh + ((size_t)(b * 64 + kc * 4 + ks) * 196) * 32);
      const uint4* gl = (const uint4*)(aTl + ((size_t)(b * 64 + kc * 4 + ks) * 196) * 32);
#pragma unroll
      for (int r = 0; r < 4; r++) {
        int e = tid + 256 * r;               // e = pos*4 + icq
        if (e < 784) {
          int pos = e >> 2, part = e & 3;
          int py = pos / 14, px = pos - py * 14;
          int dst = part * 2048 + ((py + 1) * 16 + px + 1) * 8;
          *(uint4*)(sAh + dst) = gh[e];
          *(uint4*)(sAl + dst) = gl[e];
        }
      }
    }
    // prefetch next tap's B
    {
      const int nit = (it < 35) ? it + 1 : 35;
      const int ks2 = nit / 9, tap2 = nit - ks2 * 9;
      size_t g = (size_t)tap2 * (128 * 2048) + bocbase + kc * 128 + ks2 * 32 + bicq * 8;
      pvh = *(const uint4*)(wTh + g);
      pvl = *(const uint4*)(wTl + g);
    }
    __syncthreads();

    const int t8 = ((tap / 3) * 16 + (tap % 3)) * 8;
    bf16x8 bh[2], bl[2];
#pragma unroll
    for (int nf = 0; nf < 2; nf++) {
      const int bb = q * 512 + (wn * 32 + nf * 16 + ln) * 8;
      bh[nf] = *(const bf16x8*)(sBh + bb);
      bl[nf] = *(const bf16x8*)(sBl + bb);
    }
#pragma unroll
    for (int mf = 0; mf < 7; mf++) {
      bf16x8 ah = *(const bf16x8*)(sAh + qoff + abase[mf] + t8);
      bf16x8 al = *(const bf16x8*)(sAl + qoff + abase[mf] + t8);
#pragma unroll
      for (int nf = 0; nf < 2; nf++) {
        acc[mf][nf] = __builtin_amdgcn_mfma_f32_16x16x32_bf16(ah, bh[nf], acc[mf][nf], 0, 0, 0);
        acc[mf][nf] = __builtin_amdgcn_mfma_f32_16x16x32_bf16(al, bh[nf], acc[mf][nf], 0, 0, 0);
        acc[mf][nf] = __builtin_amdgcn_mfma_f32_16x16x32_bf16(ah, bl[nf], acc[mf][nf], 0, 0, 0);
      }
    }
  }

  // p1[kc][b][pos196][oc128], coalesced 64B segments
  float* pk = p1 + ((size_t)kc * NB + b) * 196 * 128;
#pragma unroll
  for (int mf = 0; mf < 7; mf++) {
    const int row0 = wm * 112 + mf * 16 + q * 4;
#pragma unroll
    for (int nf = 0; nf < 2; nf++) {
      const int oc = nh * 64 + wn * 32 + nf * 16 + ln;
#pragma unroll
      for (int r = 0; r < 4; r++) {
        const int row = row0 + r;
        if (row < 196) pk[(size_t)row * 128 + oc] = acc[mf][nf][r];
      }
    }
  }
}

// finish: sum 16 kc slabs + bias + relu; LDS transpose -> coalesced d1[b][oc][pos] writes
__global__ __launch_bounds__(256)
void conv1_finish_p(const float* __restrict__ p1, const float* __restrict__ bias,
                    float* __restrict__ d1) {
  __shared__ float s[28 * 132];
  const int bid = blockIdx.x;       // 112 = 16 b x 7 pos-tiles(28)
  const int pt = bid % 7, b = bid / 7;
  const int tid = threadIdx.x;
#pragma unroll
  for (int r = 0; r < 4; r++) {
    int u = tid + 256 * r;
    if (u < 896) {
      int pos = u >> 5, oc4 = u & 31;
      const float* base = p1 + ((size_t)(b * 196 + pt * 28 + pos)) * 128 + oc4 * 4;
      float4 sum = ((const float4*)bias)[oc4];
#pragma unroll
      for (int k = 0; k < 16; k++) {
        float4 v = *(const float4*)(base + (size_t)k * NBP);
        sum.x += v.x; sum.y += v.y; sum.z += v.z; sum.w += v.w;
      }
      sum.x = fmaxf(sum.x, 0.f); sum.y = fmaxf(sum.y, 0.f);
      sum.z = fmaxf(sum.z, 0.f); sum.w = fmaxf(sum.w, 0.f);
      *(float4*)(s + pos * 132 + oc4 * 4) = sum;
    }
  }
  __syncthreads();
#pragma unroll
  for (int r = 0; r < 4; r++) {
    int u = tid + 256 * r;
    if (u < 896) {
      int oc = u / 7, f = u - oc * 7;
      float4 v;
      v.x = s[(f * 4 + 0) * 132 + oc];
      v.y = s[(f * 4 + 1) * 132 + oc];
      v.z = s[(f * 4 + 2) * 132 + oc];
      v.w = s[(f * 4 + 3) * 132 + oc];
      *(float4*)(d1 + ((size_t)b * 128 + oc) * 196 + pt * 28 + f * 4) = v;
    }
  }
}

// ---------------- conv2: d1 [16,128,14,14] -> partials, stride2 pad1 ----------------
__global__ void conv2_part(const float* __restrict__ d1, const float* __restrict__ w,
                           float* __restrict__ p2) {
  const int bid = blockIdx.x;
  const int kc = bid & 3, oct = (bid >> 2) & 3, b = bid >> 4;
  const int ic0 = kc * 32, oc0 = oct * 32;
  const int tid = threadIdx.x;
  const int ocl = tid >> 3, rw = tid & 7;

  __shared__ float s_in[32 * 320];
  __shared__ float s_w[32 * 324];

#pragma unroll
  for (int r = 0; r < 32; r++) {
    const int e = tid + 256 * r;
    const int ch = e >> 8, idx = e & 255;
    const int tr = idx >> 4, tc = idx & 15;
    const int iy = tr - 1, ix = tc - 1;
    float v = 0.f;
    if ((unsigned)iy < 14u && (unsigned)ix < 14u)
      v = d1[((size_t)b * 128 + ic0 + ch) * 196 + iy * 14 + ix];
    s_in[ch * 320 + tr * 20 + tc] = v;
  }
#pragma unroll
  for (int r = 0; r < 36; r++) {
    const int e = tid + 256 * r;
    const int oc = e / 288, rem = e - oc * 288;
    const int ch = rem / 9, tap = rem - ch * 9;
    s_w[ch * 324 + tap * 36 + oc] =
        w[(size_t)(oc0 + oc) * 1152 + (size_t)ic0 * 9 + rem];
  }
  __syncthreads();

  if (rw < 7) {
    float acc[7] = {};
    for (int ic = 0; ic < 32; ic++) {
      const float* wrow = s_w + ic * 324 + ocl;
      const float* irow = s_in + ic * 320;
#pragma unroll
      for (int ky = 0; ky < 3; ky++) {
        const float* r = irow + (2 * rw + ky) * 20;
        const float4 f0 = *(const float4*)(r);
        const float4 f1 = *(const float4*)(r + 4);
        const float4 f2 = *(const float4*)(r + 8);
        const float4 f3 = *(const float4*)(r + 12);
        const float ev[8] = {f0.x, f0.z, f1.x, f1.z, f2.x, f2.z, f3.x, f3.z};
        const float od[7] = {f0.y, f0.w, f1.y, f1.w, f2.y, f2.w, f3.y};
        const float w0 = wrow[(ky * 3 + 0) * 36];
        const float w1 = wrow[(ky * 3 + 1) * 36];
        const float w2 = wrow[(ky * 3 + 2) * 36];
#pragma unroll
        for (int x = 0; x < 7; x++)
          acc[x] = fmaf(w0, ev[x], fmaf(w1, od[x], fmaf(w2, ev[x + 1], acc[x])));
      }
    }
    float* po = p2 + (((size_t)kc * NB + b) * 128 + oc0 + ocl) * 49 + rw * 7;
#pragma unroll
    for (int x = 0; x < 7; x++) po[x] = acc[x];
  }
}

__global__ void conv2_finish(const float* __restrict__ p2, const float* __restrict__ bias,
                             float* __restrict__ d2) {
  const int i = blockIdx.x * 256 + threadIdx.x;
  if (i >= NB * 128 * 49) return;
  const int oc = (i / 49) & 127;
  float s = bias[oc];
#pragma unroll
  for (int k = 0; k < 4; k++) s += p2[(size_t)k * (NB * 128 * 49) + i];
  d2[i] = fmaxf(s, 0.f);
}

// ---------------- conv3: d2 [16,128,7,7] -> partials, stride2 pad1 ----------------
__global__ void conv3_part(const float* __restrict__ d2, const float* __restrict__ w,
                           float* __restrict__ p3) {
  const int bid = blockIdx.x;
  const int kc = bid & 1, oct = (bid >> 1) & 7, b = bid >> 4;
  const int ic0 = kc * 64, oc0 = oct * 16;
  const int tid = threadIdx.x;
  const int oc = tid >> 4, p = tid & 15;
  const int y = p >> 2, x = p & 3;

  __shared__ float s_in[64 * 108];
  __shared__ float s_w[64 * 144];

#pragma unroll
  for (int r = 0; r < 21; r++) {
    const int e = tid + 256 * r;
    if (e < 64 * 81) {
      const int ch = e / 81, idx = e - ch * 81;
      const int tr = idx / 9, tc = idx - tr * 9;
      const int iy = tr - 1, ix = tc - 1;
      float v = 0.f;
      if ((unsigned)iy < 7u && (unsigned)ix < 7u)
        v = d2[((size_t)b * 128 + ic0 + ch) * 49 + iy * 7 + ix];
      s_in[ch * 108 + tr * 12 + tc] = v;
    }
  }
#pragma unroll
  for (int r = 0; r < 36; r++) {
    const int e = tid + 256 * r;
    const int o = e / 576, rem = e - o * 576;
    const int ch = rem / 9, tap = rem - ch * 9;
    s_w[ch * 144 + tap * 16 + o] =
        w[(size_t)(oc0 + o) * 1152 + (size_t)ic0 * 9 + rem];
  }
  __syncthreads();

  float acc = 0.f;
  for (int ic = 0; ic < 64; ic++) {
    const float* wrow = s_w + ic * 144 + oc;
    const float* irow = s_in + ic * 108 + 2 * y * 12 + 2 * x;
#pragma unroll
    for (int ky = 0; ky < 3; ky++)
#pragma unroll
      for (int kx = 0; kx < 3; kx++)
        acc = fmaf(wrow[(ky * 3 + kx) * 16], irow[ky * 12 + kx], acc);
  }
  p3[(((size_t)kc * NB + b) * 128 + oc0 + oc) * 16 + p] = acc;
}

// ---------------- fused tidy(1x1 convs) + NMS; d3 folded in from p3 ----------------
__global__ __launch_bounds__(256, 1)
void score_nms(const float* __restrict__ d1, const float* __restrict__ d2,
               const float* __restrict__ p3, const float* __restrict__ bd3,
               const float* __restrict__ w1, const float* __restrict__ b1,
               const float* __restrict__ w2, const float* __restrict__ b2,
               const float* __restrict__ w3, const float* __restrict__ b3,
               const int* __restrict__ anchors, float* __restrict__ score,
               float* __restrict__ out_idx, float* __restrict__ out_prob,
               float* __restrict__ sel) {
  __shared__ float s_in[32 * 200];     // t1 chunks; reused linearly for d2 (6272) / d3 (2048)
  __shared__ float s_w[21 * 128];      // w1(0..5), w2(6..11), w3(12..20)
  __shared__ float s_b[21];
  __shared__ float s_sc[NA];
  __shared__ float s_bx[NA * 4];
  __shared__ float r_s[256];
  __shared__ int r_i[256];
  const int b = blockIdx.x, tid = threadIdx.x;

  for (int i = tid; i < 768; i += 256) s_w[i] = w1[i];
  for (int i = tid; i < 768; i += 256) s_w[768 + i] = w2[i];
  for (int i = tid; i < 1152; i += 256) s_w[1536 + i] = w3[i];
  if (tid < 21) s_b[tid] = (tid < 6) ? b1[tid] : (tid < 12) ? b2[tid - 6] : b3[tid - 12];
  for (int i = tid; i < NA; i += 256) {
    s_bx[i * 4 + 0] = (float)anchors[i * 4 + 0];
    s_bx[i * 4 + 1] = (float)anchors[i * 4 + 1];
    s_bx[i * 4 + 2] = (float)anchors[i * 4 + 2];
    s_bx[i * 4 + 3] = (float)anchors[i * 4 + 3];
  }

  // ---- t1: 6 oc x 196 pos = 1176 scores, d1 staged in 4 chunks of 32 ic ----
  float acc[5] = {0.f, 0.f, 0.f, 0.f, 0.f};
  for (int chunk = 0; chunk < 4; chunk++) {
    __syncthreads();
    const float* src = d1 + ((size_t)b * 128 + chunk * 32) * 196;
#pragma unroll
    for (int r = 0; r < 7; r++) {
      int e = tid + 256 * r;
      if (e < 1568) {
        int ic = e / 49, f = e - ic * 49;
        *(float4*)(s_in + ic * 200 + f * 4) = ((const float4*)(src + (size_t)ic * 196))[f];
      }
    }
    __syncthreads();
#pragma unroll
    for (int k = 0; k < 5; k++) {
      int j = tid + 256 * k;
      if (j < 1176) {
        int oc = j / 196, p = j - oc * 196;
        const float* wr = s_w + oc * 128 + chunk * 32;
        float s = acc[k];
#pragma unroll
        for (int ic = 0; ic < 32; ic++) s = fmaf(wr[ic], s_in[ic * 200 + p], s);
        acc[k] = s;
      }
    }
  }
#pragma unroll
  for (int k = 0; k < 5; k++) {
    int j = tid + 256 * k;
    if (j < 1176) {
      int oc = j / 196;
      float s = acc[k] + s_b[oc];
      s_sc[j] = s;
      score[b * NA + j] = s;
    }
  }

  // ---- t2: 6 oc x 49 = 294 scores, d2[b] staged fully (linear) ----
  __syncthreads();
  {
    const float* src = d2 + (size_t)b * 6272;
#pragma unroll
    for (int r = 0; r < 7; r++) {
      int e = tid + 256 * r;
      if (e < 1568) *(float4*)(s_in + e * 4) = ((const float4*)src)[e];
    }
  }
  __syncthreads();
#pragma unroll
  for (int k = 0; k < 2; k++) {
    int jj = tid + 256 * k;
    if (jj < 294) {
      int oc = jj / 49, p = jj - oc * 49;
      const float* wr = s_w + 768 + oc * 128;
      float s = s_b[6 + oc];
#pragma unroll 8
      for (int ic = 0; ic < 128; ic++) s = fmaf(wr[ic], s_in[ic * 49 + p], s);
      s_sc[1176 + jj] = s;
      score[b * NA + 1176 + jj] = s;
    }
  }

  // ---- t3: 9 oc x 16 = 144 scores; d3 = relu(p3[0]+p3[1]+bd3) computed inline ----
  __syncthreads();
  {
    const float4* s0 = (const float4*)(p3 + (size_t)b * 2048);
    const float4* s1 = (const float4*)(p3 + 32768 + (size_t)b * 2048);
#pragma unroll
    for (int r = 0; r < 2; r++) {
      int e = tid + 256 * r;
      if (e < 512) {
        float4 a = s0[e], c = s1[e];
        float bb = bd3[e >> 2];
        float4 v;
        v.x = fmaxf(a.x + c.x + bb, 0.f);
        v.y = fmaxf(a.y + c.y + bb, 0.f);
        v.z = fmaxf(a.z + c.z + bb, 0.f);
        v.w = fmaxf(a.w + c.w + bb, 0.f);
        *(float4*)(s_in + e * 4) = v;
      }
    }
  }
  __syncthreads();
  if (tid < 144) {
    int oc = tid >> 4, p = tid & 15;
    const float* wr = s_w + 1536 + oc * 128;
    float s = s_b[12 + oc];
#pragma unroll 8
    for (int ic = 0; ic < 128; ic++) s = fmaf(wr[ic], s_in[ic * 16 + p], s);
    s_sc[1470 + tid] = s;
    score[b * NA + 1470 + tid] = s;
  }
  __syncthreads();

  // ---- NMS: TOPN=4, IoU>0.25 suppress ----
  for (int t = 0; t < 4; t++) {
    float bs = -__builtin_inff();
    int bi = NA;
    for (int i = tid; i < NA; i += 256) {
      float s = s_sc[i];
      if (s > bs || (s == bs && i < bi)) { bs = s; bi = i; }
    }
    r_s[tid] = bs; r_i[tid] = bi;
    __syncthreads();
    for (int off = 128; off > 0; off >>= 1) {
      if (tid < off) {
        float s2 = r_s[tid + off]; int i2 = r_i[tid + off];
        if (s2 > r_s[tid] || (s2 == r_s[tid] && i2 < r_i[tid])) { r_s[tid] = s2; r_i[tid] = i2; }
      }
      __syncthreads();
    }
    const int idx = r_i[0];
    const float by0 = s_bx[idx * 4 + 0], bx0 = s_bx[idx * 4 + 1];
    const float by1 = s_bx[idx * 4 + 2], bx1 = s_bx[idx * 4 + 3];
    if (tid == 0) {
      out_idx[b * 4 + t] = (float)idx;
      out_prob[b * 4 + t] = s_sc[idx];
      sel[(b * 4 + t) * 4 + 0] = by0;
      sel[(b * 4 + t) * 4 + 1] = bx0;
      sel[(b * 4 + t) * 4 + 2] = by1;
      sel[(b * 4 + t) * 4 + 3] = bx1;
    }
    __syncthreads();
    const float a = (by1 - by0) * (bx1 - bx0);
    for (int i = tid; i < NA; i += 256) {
      float cy0 = s_bx[i * 4 + 0], cx0 = s_bx[i * 4 + 1];
      float cy1 = s_bx[i * 4 + 2], cx1 = s_bx[i * 4 + 3];
      float yy0 = fmaxf(by0, cy0), xx0 = fmaxf(bx0, cx0);
      float yy1 = fminf(by1, cy1), xx1 = fminf(bx1, cx1);
      float inter = fmaxf(yy1 - yy0, 0.f) * fmaxf(xx1 - xx0, 0.f);
      float ar = (cy1 - cy0) * (cx1 - cx0);
      float iou = inter / (a + ar - inter);
      if (iou > 0.25f) s_sc[i] = -__builtin_inff();
    }
    __syncthreads();
  }
}

// ---------------- crop+bilinear resize to [16,4,3,224,224], 4 px/thread ----------------
__global__ void crop_kernel(const float* __restrict__ x, const float* __restrict__ sel,
                            float* __restrict__ out) {
  int i4 = blockIdx.x * 256 + threadIdx.x;
  const int total4 = NB * 4 * 3 * 224 * 56;
  if (i4 >= total4) return;
  int px0 = (i4 % 56) * 4;
  int t = i4 / 56;
  int py = t % 224; t /= 224;
  int ch = t % 3;  t /= 3;
  int n  = t % 4;
  int b  = t / 4;

  const float* bx = sel + (b * 4 + n) * 4;
  const float y0 = bx[0], x0 = bx[1], y1 = bx[2], x1 = bx[3];

  float ty = (float)py / 223.0f;
  float cy = y0 + (y1 - 1.0f - y0) * ty;
  float cyf = floorf(cy);
  int ylo = (int)cyf; ylo = ylo < 0 ? 0 : (ylo > 895 ? 895 : ylo);
  int yhi = ylo + 1 > 895 ? 895 : ylo + 1;
  float wy = cy - cyf;

  const float* img = x + ((size_t)b * 3 + ch) * 448 * 448;
  auto g = [&](int yy, int xx) -> float {
    yy -= 224; xx -= 224;
    if ((unsigned)yy < 448u && (unsigned)xx < 448u)
      return img[(size_t)yy * 448 + xx];
    return 0.f;
  };

  float4 res;
  float* rp = &res.x;
#pragma unroll
  for (int k = 0; k < 4; k++) {
    float tx = (float)(px0 + k) / 223.0f;
    float cx = x0 + (x1 - 1.0f - x0) * tx;
    float cxf = floorf(cx);
    int xlo = (int)cxf; xlo = xlo < 0 ? 0 : (xlo > 895 ? 895 : xlo);
    int xhi = xlo + 1 > 895 ? 895 : xlo + 1;
    float wx = cx - cxf;
    float v00 = g(ylo, xlo), v01 = g(ylo, xhi);
    float v10 = g(yhi, xlo), v11 = g(yhi, xhi);
    rp[k] = (1.f - wy) * ((1.f - wx) * v00 + wx * v01) +
            wy * ((1.f - wx) * v10 + wx * v11);
  }
  *(float4*)(out + (size_t)i4 * 4) = res;
}

extern "C" void kernel_launch(void* const* d_in, const int* in_sizes, int n_in,
                              void* d_out, int out_size, void* d_ws, size_t ws_size,
                              hipStream_t stream) {
  const float* x    = (const float*)d_in[0];
  const float* rpn  = (const float*)d_in[1];
  const int*   anc  = (const int*)d_in[2];
  const float* w_d1 = (const float*)d_in[3];
  const float* b_d1 = (const float*)d_in[4];
  const float* w_d2 = (const float*)d_in[5];
  const float* b_d2 = (const float*)d_in[6];
  const float* w_d3 = (const float*)d_in[7];
  const float* b_d3 = (const float*)d_in[8];
  const float* w_t1 = (const float*)d_in[9];
  const float* b_t1 = (const float*)d_in[10];
  const float* w_t2 = (const float*)d_in[11];
  const float* b_t2 = (const float*)d_in[12];
  const float* w_t3 = (const float*)d_in[13];
  const float* b_t3 = (const float*)d_in[14];

  float* out = (float*)d_out;
  float* ws = (float*)d_ws;

  float* d1  = ws;                        // 401408
  float* d2  = d1 + 401408;               // 100352
  float* d3  = d2 + 100352;               // 32768 (unused slot, kept for layout stability)
  float* sel = d3 + 32768;                // 256
  float* p2  = sel + 256;                 // 401408
  float* p3  = p2 + 401408;               // 65536
  unsigned short* wTh = (unsigned short*)(p3 + 65536);   // 2,359,296 ush
  unsigned short* wTl = wTh + 2359296;                   // 2,359,296 ush
  unsigned short* aTh = wTl + 2359296;                   // 6,422,528 ush
  unsigned short* aTl = aTh + 6422528;                   // 6,422,528 ush
  // total ws need: 39,134,208 B (identical to round 5/6 verified layout)

  float* score    = out;                  // 25824
  float* out_idx  = out + 25824;          // 64
  float* out_prob = out + 25888;          // 64
  float* parts    = out + 25952;          // 9,633,792 (final crop output)
  float* p1       = parts;                // 6,422,528 floats scratch; crop overwrites after

  prep<<<dim3(10240), dim3(256), 0, stream>>>(w_d1, rpn, wTh, wTl, aTh, aTl);
  conv1_mfma<<<dim3(512), dim3(256), 0, stream>>>(aTh, aTl, wTh, wTl, p1);
  conv1_finish_p<<<dim3(112), dim3(256), 0, stream>>>(p1, b_d1, d1);
  conv2_part<<<dim3(256), dim3(256), 0, stream>>>(d1, w_d2, p2);
  conv2_finish<<<dim3(392), dim3(256), 0, stream>>>(p2, b_d2, d2);
  conv3_part<<<dim3(256), dim3(256), 0, stream>>>(d2, w_d3, p3);
  score_nms<<<dim3(16), dim3(256), 0, stream>>>(d1, d2, p3, b_d3, w_t1, b_t1, w_t2, b_t2,
                                                w_t3, b_t3, anc, score, out_idx, out_prob, sel);
  crop_kernel<<<dim3(9408), dim3(256), 0, stream>>>(x, sel, parts);
}